// Round 1
// baseline (661.212 us; speedup 1.0000x reference)
//
#include <hip/hip_runtime.h>

#define B 4
#define DIM 256
#define NH 8
#define N1 256         // 16x16 windows (source 1) per batch
#define N2 144         // 12x12 windows (source 2) per batch
#define NW 400         // N1 + N2
#define INNER 256
#define CINNER 64
#define OUT2_OFF ((size_t)16777216)   // 4*128*128*256

// ---------------------------------------------------------------------------
// helpers
// ---------------------------------------------------------------------------
static __device__ __forceinline__ const float* pixel_ptr(const float* s1, const float* s2,
                                                         int b, int n, int p, int chs) {
    if (n < N1) {
        int r = ((n >> 4) << 3) + (p >> 3);
        int c = ((n & 15) << 3) + (p & 7);
        return s1 + (((size_t)b * 128 + r) * 128 + c) * chs;
    } else {
        int nn = n - N1;
        int r = (nn / 12) * 8 + (p >> 3);
        int c = (nn % 12) * 8 + (p & 7);
        return s2 + (((size_t)b * 96 + r) * 96 + c) * chs;
    }
}

// ---------------------------------------------------------------------------
// prep: Mt[k][d] = sum_j vb_w[d][j] * v_w[j][k]   (fused value+out projection, transposed)
// grid 256 (k), block 256 (d)
// ---------------------------------------------------------------------------
__global__ void prep_kernel(const float* __restrict__ v_w, const float* __restrict__ vb_w,
                            float* __restrict__ Mt) {
    int k = blockIdx.x;
    int d = threadIdx.x;
    float s = 0.f;
    for (int j = 0; j < 256; ++j)
        s += vb_w[d * 256 + j] * v_w[j * 256 + k];
    Mt[(size_t)k * 256 + d] = s;
}

// transpose fqk_w (512x256) -> fqk_wT (256x512). grid 512 (o), block 256 (k)
__global__ void transpose_fqk(const float* __restrict__ fqk_w, float* __restrict__ fqk_wT) {
    int o = blockIdx.x;
    int k = threadIdx.x;
    fqk_wT[(size_t)k * 512 + o] = fqk_w[(size_t)o * 256 + k];
}

// ---------------------------------------------------------------------------
// stage1: per (b, window): mean over 64 pixels, QK projections + RMS norm
// grid B*NW, block 256
// ---------------------------------------------------------------------------
__global__ void stage1_kernel(const float* __restrict__ x1, const float* __restrict__ c1,
                              const float* __restrict__ x2, const float* __restrict__ c2,
                              const float* __restrict__ fqk_wT, const float* __restrict__ fqk_b,
                              const float* __restrict__ fqk_g,
                              const float* __restrict__ cqk_w, const float* __restrict__ cqk_b,
                              const float* __restrict__ cqk_g,
                              float* __restrict__ fq, float* __restrict__ fk,
                              float* __restrict__ cq, float* __restrict__ ck) {
    int blk = blockIdx.x;
    int b = blk / NW, n = blk % NW;
    int t = threadIdx.x;

    __shared__ float favg[DIM];
    __shared__ float cavg[4];
    __shared__ float red[256];

    // feature average: thread t owns channel t
    float acc = 0.f;
    for (int p = 0; p < 64; ++p) {
        const float* px = pixel_ptr(x1, x2, b, n, p, DIM);
        acc += px[t];
    }
    favg[t] = acc * (1.f / 64.f);

    // coord average: lanes 0..63 each grab one pixel (float4), wave-reduce
    if (t < 64) {
        const float* pc = pixel_ptr(c1, c2, b, n, t, 4);
        float4 v = *(const float4*)pc;
        for (int off = 32; off > 0; off >>= 1) {
            v.x += __shfl_down(v.x, off, 64);
            v.y += __shfl_down(v.y, off, 64);
            v.z += __shfl_down(v.z, off, 64);
            v.w += __shfl_down(v.w, off, 64);
        }
        if (t == 0) {
            cavg[0] = v.x * (1.f / 64.f);
            cavg[1] = v.y * (1.f / 64.f);
            cavg[2] = v.z * (1.f / 64.f);
            cavg[3] = v.w * (1.f / 64.f);
        }
    }
    __syncthreads();

    // f_qk projection: thread t computes outputs t and t+256 (coalesced via transposed W)
    float o1 = fqk_b[t], o2 = fqk_b[t + 256];
    for (int k = 0; k < DIM; ++k) {
        float fa = favg[k];
        o1 += fa * fqk_wT[(size_t)k * 512 + t];
        o2 += fa * fqk_wT[(size_t)k * 512 + 256 + t];
    }
    // RMS over the 512-vector
    red[t] = o1 * o1 + o2 * o2;
    __syncthreads();
    for (int s = 128; s > 0; s >>= 1) {
        if (t < s) red[t] += red[t + s];
        __syncthreads();
    }
    float scale = rsqrtf(red[0] / 512.f + 1e-6f);
    size_t base = ((size_t)b * NW + n) * INNER;
    fq[base + t] = o1 * scale * fqk_g[t];
    fk[base + t] = o2 * scale * fqk_g[t + 256];
    __syncthreads();

    // c_qk projection: 128 outputs from 4 inputs
    float co = 0.f;
    if (t < 128) {
        co = cqk_b[t];
        #pragma unroll
        for (int k = 0; k < 4; ++k) co += cavg[k] * cqk_w[t * 4 + k];
    }
    red[t] = (t < 128) ? co * co : 0.f;
    __syncthreads();
    for (int s = 128; s > 0; s >>= 1) {
        if (t < s) red[t] += red[t + s];
        __syncthreads();
    }
    float cscale = rsqrtf(red[0] / 128.f + 1e-6f);
    size_t cbase = ((size_t)b * NW + n) * CINNER;
    if (t < 64)       cq[cbase + t]      = co * cscale * cqk_g[t];
    else if (t < 128) ck[cbase + t - 64] = co * cscale * cqk_g[t];
}

// ---------------------------------------------------------------------------
// wproj: W[b][n][p][d] = x_window[b][n][p][:] . Mt[:][d]
// grid B*NW*2 (half-windows of 32 pixels), block 256, 32KB LDS
// ---------------------------------------------------------------------------
__global__ void wproj_kernel(const float* __restrict__ x1, const float* __restrict__ x2,
                             const float* __restrict__ Mt, float* __restrict__ W) {
    int blk = blockIdx.x;
    int half = blk & 1;
    int bn = blk >> 1;
    int b = bn / NW, n = bn % NW;
    int t = threadIdx.x;

    __shared__ float xs[32][DIM];
    int p0 = half * 32;
    for (int i = 0; i < 32; ++i) {
        const float* px = pixel_ptr(x1, x2, b, n, p0 + i, DIM);
        xs[i][t] = px[t];
    }
    __syncthreads();

    int tx = t & 63;   // cols tx*4 .. tx*4+3
    int ty = t >> 6;   // rows ty*8 .. ty*8+7
    float acc[8][4] = {};
    for (int k = 0; k < DIM; ++k) {
        float4 mv = *(const float4*)(Mt + (size_t)k * DIM + tx * 4);
        #pragma unroll
        for (int i = 0; i < 8; ++i) {
            float xv = xs[ty * 8 + i][k];
            acc[i][0] += xv * mv.x;
            acc[i][1] += xv * mv.y;
            acc[i][2] += xv * mv.z;
            acc[i][3] += xv * mv.w;
        }
    }
    float* wout = W + (((size_t)b * NW + n) * 64 + p0) * DIM;
    #pragma unroll
    for (int i = 0; i < 8; ++i) {
        *(float4*)(wout + (size_t)(ty * 8 + i) * DIM + tx * 4) =
            make_float4(acc[i][0], acc[i][1], acc[i][2], acc[i][3]);
    }
}

// ---------------------------------------------------------------------------
// scores + softmax: one block per (b, h, n) row. P[b][h][n][m], masked entries = 0
// grid B*NH*NW, block 256
// ---------------------------------------------------------------------------
__global__ void scores_kernel(const float* __restrict__ fq, const float* __restrict__ fk,
                              const float* __restrict__ cq, const float* __restrict__ ck,
                              float* __restrict__ P) {
    int blk = blockIdx.x;
    int n = blk % NW;
    int bh = blk / NW;
    int h = bh % NH, b = bh / NH;
    int t = threadIdx.x;

    __shared__ float qf[32];
    __shared__ float qc[8];
    __shared__ float red[256];

    if (t < 32)            qf[t]      = fq[((size_t)b * NW + n) * INNER + h * 32 + t];
    else if (t < 40)       qc[t - 32] = cq[((size_t)b * NW + n) * CINNER + h * 8 + (t - 32)];
    __syncthreads();

    bool n_src1 = (n < N1);
    // m = t (always valid), m2 = t + 256 (valid if t < 144)
    int m0 = t, m1 = t + 256;
    bool a0 = n_src1 != (m0 < N1);
    bool a1 = (t < 144) && (n_src1 != (m1 < N1));

    float s0 = -3.4e38f, s1 = -3.4e38f;
    if (a0) {
        const float* fkr = fk + ((size_t)b * NW + m0) * INNER + h * 32;
        const float* ckr = ck + ((size_t)b * NW + m0) * CINNER + h * 8;
        float sf = 0.f, sc = 0.f;
        #pragma unroll
        for (int j = 0; j < 32; ++j) sf += qf[j] * fkr[j];
        #pragma unroll
        for (int j = 0; j < 8; ++j) sc += qc[j] * ckr[j];
        s0 = sf * 0.17677669529663687f + sc * 0.35355339059327373f;
    }
    if (a1) {
        const float* fkr = fk + ((size_t)b * NW + m1) * INNER + h * 32;
        const float* ckr = ck + ((size_t)b * NW + m1) * CINNER + h * 8;
        float sf = 0.f, sc = 0.f;
        #pragma unroll
        for (int j = 0; j < 32; ++j) sf += qf[j] * fkr[j];
        #pragma unroll
        for (int j = 0; j < 8; ++j) sc += qc[j] * ckr[j];
        s1 = sf * 0.17677669529663687f + sc * 0.35355339059327373f;
    }

    // block max
    red[t] = fmaxf(s0, s1);
    __syncthreads();
    for (int s = 128; s > 0; s >>= 1) {
        if (t < s) red[t] = fmaxf(red[t], red[t + s]);
        __syncthreads();
    }
    float mx = red[0];
    __syncthreads();

    float e0 = a0 ? __expf(s0 - mx) : 0.f;
    float e1 = a1 ? __expf(s1 - mx) : 0.f;
    red[t] = e0 + e1;
    __syncthreads();
    for (int s = 128; s > 0; s >>= 1) {
        if (t < s) red[t] += red[t + s];
        __syncthreads();
    }
    float inv = 1.f / red[0];

    float* prow = P + (((size_t)(b * NH + h) * NW) + n) * NW;
    prow[m0] = e0 * inv;
    if (t < 144) prow[m1] = e1 * inv;
}

// ---------------------------------------------------------------------------
// pv: out[b][n][pix][:] = sum_m P[b][h][n][m] * W[b][m][pix][:], fused un-window
// grid B*NH*8*13, block 256. Skips masked K-ranges entirely.
// ---------------------------------------------------------------------------
__global__ void pv_kernel(const float* __restrict__ P, const float* __restrict__ W,
                          float* __restrict__ out) {
    int blk = blockIdx.x;
    int ntile = blk % 13;
    int rest = blk / 13;
    int pih = rest & 7;
    rest >>= 3;
    int h = rest % NH, b = rest / NH;
    int pix = h * 8 + pih;
    int n0 = ntile * 32;
    int t = threadIdx.x;
    int tx = t & 63;   // cols tx*4..
    int ty = t >> 6;   // rows ty*8..

    __shared__ float Ps[32][64];
    float acc[8][4] = {};

    int mlo = (n0 < N1) ? N1 : 0;
    int mhi = (n0 < N1) ? NW : N1;
    const float* Pbase = P + (size_t)(b * NH + h) * NW * NW;

    for (int m0 = mlo; m0 < mhi; m0 += 64) {
        int mc = min(64, mhi - m0);
        __syncthreads();
        for (int idx = t; idx < 32 * 64; idx += 256) {
            int r = idx >> 6, mm = idx & 63;
            int nn = n0 + r;
            float v = 0.f;
            if (mm < mc && nn < NW) v = Pbase[(size_t)nn * NW + m0 + mm];
            Ps[r][mm] = v;
        }
        __syncthreads();
        for (int mm = 0; mm < mc; ++mm) {
            const float* wrow = W + (((size_t)b * NW + m0 + mm) * 64 + pix) * DIM + tx * 4;
            float4 wv = *(const float4*)wrow;
            #pragma unroll
            for (int i = 0; i < 8; ++i) {
                float p = Ps[ty * 8 + i][mm];
                acc[i][0] += p * wv.x;
                acc[i][1] += p * wv.y;
                acc[i][2] += p * wv.z;
                acc[i][3] += p * wv.w;
            }
        }
    }

    int pr = pix >> 3, pc = pix & 7;
    #pragma unroll
    for (int i = 0; i < 8; ++i) {
        int n = n0 + ty * 8 + i;
        if (n >= NW) break;
        float* optr;
        if (n < N1) {
            int wr = n >> 4, wc = n & 15;
            optr = out + (((size_t)b * 128 + wr * 8 + pr) * 128 + wc * 8 + pc) * DIM;
        } else {
            int nn = n - N1;
            int wr = nn / 12, wc = nn % 12;
            optr = out + OUT2_OFF + (((size_t)b * 96 + wr * 8 + pr) * 96 + wc * 8 + pc) * DIM;
        }
        *(float4*)(optr + tx * 4) = make_float4(acc[i][0], acc[i][1], acc[i][2], acc[i][3]);
    }
}

// ---------------------------------------------------------------------------
extern "C" void kernel_launch(void* const* d_in, const int* in_sizes, int n_in,
                              void* d_out, int out_size, void* d_ws, size_t ws_size,
                              hipStream_t stream) {
    const float* x1    = (const float*)d_in[0];
    const float* c1    = (const float*)d_in[1];
    const float* x2    = (const float*)d_in[2];
    const float* c2    = (const float*)d_in[3];
    const float* fqk_w = (const float*)d_in[4];
    const float* fqk_b = (const float*)d_in[5];
    const float* fqk_g = (const float*)d_in[6];
    const float* cqk_w = (const float*)d_in[7];
    const float* cqk_b = (const float*)d_in[8];
    const float* cqk_g = (const float*)d_in[9];
    const float* v_w   = (const float*)d_in[10];
    const float* vb_w  = (const float*)d_in[11];
    float* out = (float*)d_out;

    float* ws     = (float*)d_ws;
    float* Mt     = ws;                          // 256*256
    float* fqk_wT = Mt + 256 * 256;              // 256*512
    float* fq     = fqk_wT + 256 * 512;          // B*NW*INNER
    float* fk     = fq + (size_t)B * NW * INNER;
    float* cq     = fk + (size_t)B * NW * INNER; // B*NW*CINNER
    float* ck     = cq + (size_t)B * NW * CINNER;
    float* P      = ck + (size_t)B * NW * CINNER;          // B*NH*NW*NW
    float* W      = P + (size_t)B * NH * NW * NW;          // B*NW*64*DIM

    prep_kernel<<<256, 256, 0, stream>>>(v_w, vb_w, Mt);
    transpose_fqk<<<512, 256, 0, stream>>>(fqk_w, fqk_wT);
    stage1_kernel<<<B * NW, 256, 0, stream>>>(x1, c1, x2, c2, fqk_wT, fqk_b, fqk_g,
                                              cqk_w, cqk_b, cqk_g, fq, fk, cq, ck);
    wproj_kernel<<<B * NW * 2, 256, 0, stream>>>(x1, x2, Mt, W);
    scores_kernel<<<B * NH * NW, 256, 0, stream>>>(fq, fk, cq, ck, P);
    pv_kernel<<<B * NH * 8 * 13, 256, 0, stream>>>(P, W, out);
}

// Round 2
// 431.159 us; speedup vs baseline: 1.5336x; 1.5336x over previous
//
#include <hip/hip_runtime.h>
#include <hip/hip_bf16.h>

#define B 4
#define DIM 256
#define NH 8
#define N1 256
#define N2 144
#define NW 400
#define INNER 256
#define CINNER 64
#define OUT2_OFF ((size_t)16777216)   // 4*128*128*256

typedef __attribute__((ext_vector_type(8))) short short8v;
typedef __attribute__((ext_vector_type(4))) float f32x4;
typedef __attribute__((ext_vector_type(2))) unsigned uint2v;
typedef __attribute__((ext_vector_type(4))) unsigned uint4v;

static __device__ __forceinline__ short f2bf(float f) {
    __hip_bfloat16 h = __float2bfloat16(f);
    return __builtin_bit_cast(short, h);
}

static __device__ __forceinline__ const float* pixel_ptr(const float* s1, const float* s2,
                                                         int b, int n, int p, int chs) {
    if (n < N1) {
        int r = ((n >> 4) << 3) + (p >> 3);
        int c = ((n & 15) << 3) + (p & 7);
        return s1 + (((size_t)b * 128 + r) * 128 + c) * chs;
    } else {
        int nn = n - N1;
        int r = (nn / 12) * 8 + (p >> 3);
        int c = (nn % 12) * 8 + (p & 7);
        return s2 + (((size_t)b * 96 + r) * 96 + c) * chs;
    }
}

// ---------------------------------------------------------------------------
// prep: Mb[d][k] = sum_j vb_w[d][j] * v_w[j][k]  (bf16, row-major [d][k])
// grid 256 (d), block 256 (k)
// ---------------------------------------------------------------------------
__global__ void prep_kernel(const float* __restrict__ v_w, const float* __restrict__ vb_w,
                            short* __restrict__ Mb) {
    int d = blockIdx.x;
    int k = threadIdx.x;
    float s = 0.f;
    for (int j = 0; j < 256; ++j)
        s += vb_w[d * 256 + j] * v_w[j * 256 + k];
    Mb[(size_t)d * 256 + k] = f2bf(s);
}

__global__ void transpose_fqk(const float* __restrict__ fqk_w, float* __restrict__ fqk_wT) {
    int o = blockIdx.x;
    int k = threadIdx.x;
    fqk_wT[(size_t)k * 512 + o] = fqk_w[(size_t)o * 256 + k];
}

// ---------------------------------------------------------------------------
// stage1: per (b, window): mean over 64 pixels, QK projections + RMS norm (fp32)
// ---------------------------------------------------------------------------
__global__ void stage1_kernel(const float* __restrict__ x1, const float* __restrict__ c1,
                              const float* __restrict__ x2, const float* __restrict__ c2,
                              const float* __restrict__ fqk_wT, const float* __restrict__ fqk_b,
                              const float* __restrict__ fqk_g,
                              const float* __restrict__ cqk_w, const float* __restrict__ cqk_b,
                              const float* __restrict__ cqk_g,
                              float* __restrict__ fq, float* __restrict__ fk,
                              float* __restrict__ cq, float* __restrict__ ck) {
    int blk = blockIdx.x;
    int b = blk / NW, n = blk % NW;
    int t = threadIdx.x;

    __shared__ float favg[DIM];
    __shared__ float cavg[4];
    __shared__ float red[256];

    float acc = 0.f;
    for (int p = 0; p < 64; ++p) {
        const float* px = pixel_ptr(x1, x2, b, n, p, DIM);
        acc += px[t];
    }
    favg[t] = acc * (1.f / 64.f);

    if (t < 64) {
        const float* pc = pixel_ptr(c1, c2, b, n, t, 4);
        float4 v = *(const float4*)pc;
        for (int off = 32; off > 0; off >>= 1) {
            v.x += __shfl_down(v.x, off, 64);
            v.y += __shfl_down(v.y, off, 64);
            v.z += __shfl_down(v.z, off, 64);
            v.w += __shfl_down(v.w, off, 64);
        }
        if (t == 0) {
            cavg[0] = v.x * (1.f / 64.f);
            cavg[1] = v.y * (1.f / 64.f);
            cavg[2] = v.z * (1.f / 64.f);
            cavg[3] = v.w * (1.f / 64.f);
        }
    }
    __syncthreads();

    float o1 = fqk_b[t], o2 = fqk_b[t + 256];
    for (int k = 0; k < DIM; ++k) {
        float fa = favg[k];
        o1 += fa * fqk_wT[(size_t)k * 512 + t];
        o2 += fa * fqk_wT[(size_t)k * 512 + 256 + t];
    }
    red[t] = o1 * o1 + o2 * o2;
    __syncthreads();
    for (int s = 128; s > 0; s >>= 1) {
        if (t < s) red[t] += red[t + s];
        __syncthreads();
    }
    float scale = rsqrtf(red[0] / 512.f + 1e-6f);
    size_t base = ((size_t)b * NW + n) * INNER;
    fq[base + t] = o1 * scale * fqk_g[t];
    fk[base + t] = o2 * scale * fqk_g[t + 256];
    __syncthreads();

    float co = 0.f;
    if (t < 128) {
        co = cqk_b[t];
        #pragma unroll
        for (int k = 0; k < 4; ++k) co += cavg[k] * cqk_w[t * 4 + k];
    }
    red[t] = (t < 128) ? co * co : 0.f;
    __syncthreads();
    for (int s = 128; s > 0; s >>= 1) {
        if (t < s) red[t] += red[t + s];
        __syncthreads();
    }
    float cscale = rsqrtf(red[0] / 128.f + 1e-6f);
    size_t cbase = ((size_t)b * NW + n) * CINNER;
    if (t < 64)       cq[cbase + t]      = co * cscale * cqk_g[t];
    else if (t < 128) ck[cbase + t - 64] = co * cscale * cqk_g[t];
}

// ---------------------------------------------------------------------------
// scores + softmax: one block per (b, h, n) row. Pb bf16, rows padded to 512,
// row stride 416.
// ---------------------------------------------------------------------------
__global__ void scores_kernel(const float* __restrict__ fq, const float* __restrict__ fk,
                              const float* __restrict__ cq, const float* __restrict__ ck,
                              short* __restrict__ Pb) {
    int blk = blockIdx.x;
    int n = blk % NW;
    int bh = blk / NW;
    int h = bh % NH, b = bh / NH;
    int t = threadIdx.x;

    __shared__ float qf[32];
    __shared__ float qc[8];
    __shared__ float red[256];

    if (t < 32)            qf[t]      = fq[((size_t)b * NW + n) * INNER + h * 32 + t];
    else if (t < 40)       qc[t - 32] = cq[((size_t)b * NW + n) * CINNER + h * 8 + (t - 32)];
    __syncthreads();

    bool n_src1 = (n < N1);
    int m0 = t, m1 = t + 256;
    bool a0 = n_src1 != (m0 < N1);
    bool a1 = (t < 144) && (n_src1 != (m1 < N1));

    float s0 = -3.4e38f, s1 = -3.4e38f;
    if (a0) {
        const float* fkr = fk + ((size_t)b * NW + m0) * INNER + h * 32;
        const float* ckr = ck + ((size_t)b * NW + m0) * CINNER + h * 8;
        float sf = 0.f, sc = 0.f;
        #pragma unroll
        for (int j = 0; j < 32; ++j) sf += qf[j] * fkr[j];
        #pragma unroll
        for (int j = 0; j < 8; ++j) sc += qc[j] * ckr[j];
        s0 = sf * 0.17677669529663687f + sc * 0.35355339059327373f;
    }
    if (a1) {
        const float* fkr = fk + ((size_t)b * NW + m1) * INNER + h * 32;
        const float* ckr = ck + ((size_t)b * NW + m1) * CINNER + h * 8;
        float sf = 0.f, sc = 0.f;
        #pragma unroll
        for (int j = 0; j < 32; ++j) sf += qf[j] * fkr[j];
        #pragma unroll
        for (int j = 0; j < 8; ++j) sc += qc[j] * ckr[j];
        s1 = sf * 0.17677669529663687f + sc * 0.35355339059327373f;
    }

    red[t] = fmaxf(s0, s1);
    __syncthreads();
    for (int s = 128; s > 0; s >>= 1) {
        if (t < s) red[t] = fmaxf(red[t], red[t + s]);
        __syncthreads();
    }
    float mx = red[0];
    __syncthreads();

    float e0 = a0 ? __expf(s0 - mx) : 0.f;
    float e1 = a1 ? __expf(s1 - mx) : 0.f;
    red[t] = e0 + e1;
    __syncthreads();
    for (int s = 128; s > 0; s >>= 1) {
        if (t < s) red[t] += red[t + s];
        __syncthreads();
    }
    float inv = 1.f / red[0];

    short* prow = Pb + ((size_t)(b * 8 + h) * 512 + n) * 416;
    prow[m0] = f2bf(e0 * inv);
    if (t < 144) prow[m1] = f2bf(e1 * inv);
}

// ---------------------------------------------------------------------------
// wproj_mfma: W^T orientation: D[row=d][col=R] = sum_k Mb[d][k] * X[R][k]
// A = Mb (bf16 global, k-contiguous), B = X rows (fp32->bf16 in regs).
// Block: 128 d x 256 R (4 windows), 4 waves 2x2, wave = 64d x 128R.
// Wb[b][m][p][d] bf16, packed 8B stores (4 consecutive d per lane).
// grid = 400 rt * 2 dt
// ---------------------------------------------------------------------------
__global__ __launch_bounds__(256, 2) void wproj_mfma(
    const float* __restrict__ x1, const float* __restrict__ x2,
    const short* __restrict__ Mb, short* __restrict__ Wb) {
    int bid = blockIdx.x;
    int dt = bid & 1;
    int rt = bid >> 1;            // 0..399
    int tid = threadIdx.x;
    int lane = tid & 63;
    int w = tid >> 6;
    int wr = w >> 1;              // d half
    int wc = w & 1;               // R half
    int l15 = lane & 15;
    int kl = (lane >> 4) << 3;    // 0,8,16,24

    int b = rt / 100;
    int nb0 = (rt % 100) * 4;

    const float* rp[8];
    #pragma unroll
    for (int ni = 0; ni < 8; ++ni) {
        int Rl = wc * 128 + ni * 16 + l15;
        int n = nb0 + (Rl >> 6);
        int p = Rl & 63;
        rp[ni] = pixel_ptr(x1, x2, b, n, p, 256) + kl;
    }
    const short* ap[4];
    #pragma unroll
    for (int mi = 0; mi < 4; ++mi) {
        int d = dt * 128 + wr * 64 + mi * 16 + l15;
        ap[mi] = Mb + (size_t)d * 256 + kl;
    }

    f32x4 acc[4][8] = {};
    for (int k0 = 0; k0 < 256; k0 += 32) {
        short8v af[4];
        #pragma unroll
        for (int mi = 0; mi < 4; ++mi)
            af[mi] = *(const short8v*)(ap[mi] + k0);
        #pragma unroll
        for (int ni = 0; ni < 8; ++ni) {
            const float* src = rp[ni] + k0;
            float4 f0 = *(const float4*)src;
            float4 f1 = *(const float4*)(src + 4);
            short8v bf;
            bf[0] = f2bf(f0.x); bf[1] = f2bf(f0.y); bf[2] = f2bf(f0.z); bf[3] = f2bf(f0.w);
            bf[4] = f2bf(f1.x); bf[5] = f2bf(f1.y); bf[6] = f2bf(f1.z); bf[7] = f2bf(f1.w);
            #pragma unroll
            for (int mi = 0; mi < 4; ++mi)
                acc[mi][ni] = __builtin_amdgcn_mfma_f32_16x16x32_bf16(af[mi], bf, acc[mi][ni], 0, 0, 0);
        }
    }

    int dq = dt * 128 + wr * 64 + ((lane >> 4) << 2);
    #pragma unroll
    for (int ni = 0; ni < 8; ++ni) {
        size_t Rg = (size_t)rt * 256 + wc * 128 + ni * 16 + l15;
        short* wp = Wb + Rg * 256 + dq;
        #pragma unroll
        for (int mi = 0; mi < 4; ++mi) {
            f32x4 a = acc[mi][ni];
            short4 s4 = make_short4(f2bf(a.x), f2bf(a.y), f2bf(a.z), f2bf(a.w));
            *(short4*)(wp + mi * 16) = s4;
        }
    }
}

// ---------------------------------------------------------------------------
// pv_mfma: per (b,p): out[n][d] = sum_m P_h[n][m] * W[m][p][d]
// A = Pb rows (m-contiguous), B = Wb staged to LDS in tr-subtiled layout,
// read via ds_read_b64_tr_b16. Block 128n x 128d, 4 waves 2x2 (64x64 each).
// grid = b4 * p64 * nt4 * dt2; masked K-ranges skipped.
// ---------------------------------------------------------------------------
__global__ __launch_bounds__(256, 2) void pv_mfma(
    const short* __restrict__ Pb, const short* __restrict__ Wb,
    float* __restrict__ out) {
    int bid = blockIdx.x;
    int dt = bid & 1;
    int nt = (bid >> 1) & 3;
    int p  = (bid >> 3) & 63;
    int b  = bid >> 9;
    int h  = p >> 3;
    int tid = threadIdx.x;
    int lane = tid & 63;
    int w = tid >> 6;
    int wr = w >> 1;
    int wc = w & 1;
    int l15 = lane & 15;
    int kl8 = (lane >> 4) << 3;

    __shared__ short8v Bs[512];   // 8KB: [par2][nb8][g4][r4][c0h2] of 16B chunks
    unsigned ldsBase = (unsigned)(size_t)&Bs[0];

    int n0 = nt * 128;
    int mlo = (nt < 2) ? 256 : 0;
    int mhi = (nt < 2) ? 400 : 256;
    int d0 = dt * 128;

    const short* arow[4];
    #pragma unroll
    for (int mi = 0; mi < 4; ++mi) {
        int n = n0 + wr * 64 + mi * 16 + l15;
        arow[mi] = Pb + ((size_t)(b * 8 + h) * 512 + n) * 416 + kl8;
    }

    f32x4 acc[4][4] = {};

    // staging helpers (2 chunks per thread)
    int mrow0 = tid >> 4;             // chunk i=0
    int doff0 = (tid & 15) << 3;
    int mrow1 = (tid + 256) >> 4;
    int doff1 = doff0;

    const size_t wbBase = ((size_t)b * 400) * 64 * 256 + (size_t)p * 256 + d0;

    short8v cur0, cur1;
    {
        int gm0 = mlo + mrow0, gm1 = mlo + mrow1;
        cur0 = (gm0 < mhi) ? *(const short8v*)(Wb + wbBase + (size_t)gm0 * 64 * 256 + doff0) : (short8v)0;
        cur1 = (gm1 < mhi) ? *(const short8v*)(Wb + wbBase + (size_t)gm1 * 64 * 256 + doff1) : (short8v)0;
    }

    for (int m0 = mlo; m0 < mhi; m0 += 32) {
        // A-frags early (global, no LDS dependence)
        short8v af[4];
        #pragma unroll
        for (int mi = 0; mi < 4; ++mi)
            af[mi] = *(const short8v*)(arow[mi] + m0);

        __syncthreads();   // protect LDS from previous iteration's readers
        {
            int par = (mrow0 >> 2) & 1, g = mrow0 >> 3, r = mrow0 & 3;
            int nb = doff0 >> 4, c0h = (doff0 >> 3) & 1;
            Bs[(par * 8 + nb) * 32 + g * 8 + r * 2 + c0h] = cur0;
            par = (mrow1 >> 2) & 1; g = mrow1 >> 3; r = mrow1 & 3;
            nb = doff1 >> 4; c0h = (doff1 >> 3) & 1;
            Bs[(par * 8 + nb) * 32 + g * 8 + r * 2 + c0h] = cur1;
        }
        // prefetch next tile while barrier/compute run
        if (m0 + 32 < mhi) {
            int gm0 = m0 + 32 + mrow0, gm1 = m0 + 32 + mrow1;
            cur0 = (gm0 < mhi) ? *(const short8v*)(Wb + wbBase + (size_t)gm0 * 64 * 256 + doff0) : (short8v)0;
            cur1 = (gm1 < mhi) ? *(const short8v*)(Wb + wbBase + (size_t)gm1 * 64 * 256 + doff1) : (short8v)0;
        }
        __syncthreads();

        short8v bf[4];
        #pragma unroll
        for (int ni = 0; ni < 4; ++ni) {
            int nb = wc * 4 + ni;
            unsigned a0 = ldsBase + (unsigned)((0 * 8 + nb) * 512 + lane * 8);
            unsigned a1 = ldsBase + (unsigned)((1 * 8 + nb) * 512 + lane * 8);
            uint2v lo, hi;
            asm volatile("ds_read_b64_tr_b16 %0, %1" : "=v"(lo) : "v"(a0));
            asm volatile("ds_read_b64_tr_b16 %0, %1" : "=v"(hi) : "v"(a1));
            uint4v bw; bw.x = lo.x; bw.y = lo.y; bw.z = hi.x; bw.w = hi.y;
            bf[ni] = __builtin_bit_cast(short8v, bw);
        }
        asm volatile("s_waitcnt lgkmcnt(0)" ::: "memory");
        __builtin_amdgcn_sched_barrier(0);

        #pragma unroll
        for (int mi = 0; mi < 4; ++mi) {
            #pragma unroll
            for (int ni = 0; ni < 4; ++ni)
                acc[mi][ni] = __builtin_amdgcn_mfma_f32_16x16x32_bf16(af[mi], bf[ni], acc[mi][ni], 0, 0, 0);
        }
    }

    int pr = p >> 3, pc = p & 7;
    #pragma unroll
    for (int mi = 0; mi < 4; ++mi) {
        #pragma unroll
        for (int r = 0; r < 4; ++r) {
            int n = n0 + wr * 64 + mi * 16 + ((lane >> 4) << 2) + r;
            if (n >= NW) continue;
            float* obase;
            if (n < N1) {
                obase = out + (((size_t)b * 128 + (n >> 4) * 8 + pr) * 128 + ((n & 15) << 3) + pc) * 256;
            } else {
                int nn = n - N1;
                obase = out + OUT2_OFF + (((size_t)b * 96 + (nn / 12) * 8 + pr) * 96 + (nn % 12) * 8 + pc) * 256;
            }
            #pragma unroll
            for (int ni = 0; ni < 4; ++ni)
                obase[d0 + wc * 64 + ni * 16 + l15] = acc[mi][ni][r];
        }
    }
}

// ---------------------------------------------------------------------------
extern "C" void kernel_launch(void* const* d_in, const int* in_sizes, int n_in,
                              void* d_out, int out_size, void* d_ws, size_t ws_size,
                              hipStream_t stream) {
    const float* x1    = (const float*)d_in[0];
    const float* c1    = (const float*)d_in[1];
    const float* x2    = (const float*)d_in[2];
    const float* c2    = (const float*)d_in[3];
    const float* fqk_w = (const float*)d_in[4];
    const float* fqk_b = (const float*)d_in[5];
    const float* fqk_g = (const float*)d_in[6];
    const float* cqk_w = (const float*)d_in[7];
    const float* cqk_b = (const float*)d_in[8];
    const float* cqk_g = (const float*)d_in[9];
    const float* v_w   = (const float*)d_in[10];
    const float* vb_w  = (const float*)d_in[11];
    float* out = (float*)d_out;

    char* wsb = (char*)d_ws;
    short* Mb     = (short*)(wsb);                    // 131,072 B
    float* fqk_wT = (float*)(wsb + 131072);           // 524,288 B
    float* fq     = (float*)(wsb + 655360);           // 1,638,400 B
    float* fk     = (float*)(wsb + 2293760);          // 1,638,400 B
    float* cq     = (float*)(wsb + 3932160);          // 409,600 B
    float* ck     = (float*)(wsb + 4341760);          // 409,600 B
    short* Pb     = (short*)(wsb + 4751360);          // 4*8*512*416*2 = 13,631,488 B
    short* Wb     = (short*)(wsb + 18382848);         // 102400*256*2 = 52,428,800 B

    prep_kernel<<<256, 256, 0, stream>>>(v_w, vb_w, Mb);
    transpose_fqk<<<512, 256, 0, stream>>>(fqk_w, fqk_wT);
    stage1_kernel<<<B * NW, 256, 0, stream>>>(x1, c1, x2, c2, fqk_wT, fqk_b, fqk_g,
                                              cqk_w, cqk_b, cqk_g, fq, fk, cq, ck);
    wproj_mfma<<<800, 256, 0, stream>>>(x1, x2, Mb, Wb);
    scores_kernel<<<B * NH * NW, 256, 0, stream>>>(fq, fk, cq, ck, Pb);
    pv_mfma<<<2048, 256, 0, stream>>>(Pb, Wb, out);
}

// Round 4
// 353.071 us; speedup vs baseline: 1.8727x; 1.2212x over previous
//
#include <hip/hip_runtime.h>
#include <hip/hip_bf16.h>

#define B 4
#define NH 8
#define N1 256
#define N2 144
#define NW 400
#define OUT2_OFF ((size_t)16777216)   // 4*128*128*256

typedef __attribute__((ext_vector_type(8))) short short8v;
typedef __attribute__((ext_vector_type(4))) float f32x4;
typedef __attribute__((ext_vector_type(2))) unsigned uint2v;
typedef __attribute__((ext_vector_type(4))) unsigned uint4v;

static __device__ __forceinline__ short f2bf(float f) {
    __hip_bfloat16 h = __float2bfloat16(f);
    return __builtin_bit_cast(short, h);
}

// ---------------------------------------------------------------------------
// prep: M = vb_w @ v_w fused (256x256), stored in MFMA-A-frag order:
// Mbf[(dtile*8 + kc)*512 + kgrp*128 + (d&15)*8 + (k&7)]
// so af load = base(dtile,kc) + lane*8  (fully coalesced).
// NOTE: Mbf spans 256*256 shorts = 131072 BYTES (round-3 bug: was given 64KB).
// ---------------------------------------------------------------------------
__global__ void prep_kernel(const float* __restrict__ v_w, const float* __restrict__ vb_w,
                            short* __restrict__ Mbf) {
    int d = blockIdx.x;
    int k = threadIdx.x;
    float s = 0.f;
    for (int j = 0; j < 256; ++j)
        s += vb_w[d * 256 + j] * v_w[j * 256 + k];
    size_t idx = ((((size_t)((d >> 4) * 8 + (k >> 5))) * 4 + ((k >> 3) & 3)) * 16 + (d & 15)) * 8 + (k & 7);
    Mbf[idx] = f2bf(s);
}

__global__ void transpose_fqk(const float* __restrict__ fqk_w, float* __restrict__ fqk_wT) {
    int o = blockIdx.x;
    int k = threadIdx.x;
    fqk_wT[(size_t)k * 512 + o] = fqk_w[(size_t)o * 256 + k];
}

// ---------------------------------------------------------------------------
// stage1: per (b, window): mean, QK proj + RMS (fp32 math), emits:
//   qcat/kcat bf16 [b][h][n][64] (scaled, k=[0:32] feat, [32:40] coord, [40:64] zero)
//   Xw3 bf16 [rt=400][kc=8][Rloc=256][32]  (k-chunked windowed X for wproj)
// ---------------------------------------------------------------------------
__global__ void stage1_kernel(const float* __restrict__ x1, const float* __restrict__ c1,
                              const float* __restrict__ x2, const float* __restrict__ c2,
                              const float* __restrict__ fqk_wT, const float* __restrict__ fqk_b,
                              const float* __restrict__ fqk_g,
                              const float* __restrict__ cqk_w, const float* __restrict__ cqk_b,
                              const float* __restrict__ cqk_g,
                              short* __restrict__ qcat, short* __restrict__ kcat,
                              short* __restrict__ Xw3) {
    int blk = blockIdx.x;
    int b = blk / NW, n = blk % NW;
    int t = threadIdx.x;

    __shared__ float favg[256];
    __shared__ float cavg[4];
    __shared__ float red[256];

    const float* xbase;
    int rstride;
    if (n < N1) {
        xbase = x1 + (((size_t)b * 128 + (n >> 4) * 8) * 128 + (n & 15) * 8) * 256;
        rstride = 128 * 256;
    } else {
        int nn = n - N1;
        xbase = x2 + (((size_t)b * 96 + (nn / 12) * 8) * 96 + (nn % 12) * 8) * 256;
        rstride = 96 * 256;
    }

    int rt = b * 100 + (n >> 2);
    int RlocBase = (n & 3) * 64;
    short* xw_base = Xw3 + (((size_t)rt * 8 + (t >> 5)) * 256) * 32 + (t & 31);

    float acc = 0.f;
    #pragma unroll 4
    for (int p = 0; p < 64; ++p) {
        float v = xbase[(p >> 3) * rstride + (p & 7) * 256 + t];
        acc += v;
        xw_base[(RlocBase + p) * 32] = f2bf(v);
    }
    favg[t] = acc * (1.f / 64.f);

    if (t < 64) {
        const float* cbase;
        int crs;
        if (n < N1) {
            cbase = c1 + (((size_t)b * 128 + (n >> 4) * 8) * 128 + (n & 15) * 8) * 4;
            crs = 128 * 4;
        } else {
            int nn = n - N1;
            cbase = c2 + (((size_t)b * 96 + (nn / 12) * 8) * 96 + (nn % 12) * 8) * 4;
            crs = 96 * 4;
        }
        float4 v = *(const float4*)(cbase + (t >> 3) * crs + (t & 7) * 4);
        for (int off = 32; off > 0; off >>= 1) {
            v.x += __shfl_down(v.x, off, 64);
            v.y += __shfl_down(v.y, off, 64);
            v.z += __shfl_down(v.z, off, 64);
            v.w += __shfl_down(v.w, off, 64);
        }
        if (t == 0) {
            cavg[0] = v.x * (1.f / 64.f);
            cavg[1] = v.y * (1.f / 64.f);
            cavg[2] = v.z * (1.f / 64.f);
            cavg[3] = v.w * (1.f / 64.f);
        }
    }
    __syncthreads();

    float o1 = fqk_b[t], o2 = fqk_b[t + 256];
    for (int k = 0; k < 256; ++k) {
        float fa = favg[k];
        o1 += fa * fqk_wT[(size_t)k * 512 + t];
        o2 += fa * fqk_wT[(size_t)k * 512 + 256 + t];
    }
    red[t] = o1 * o1 + o2 * o2;
    __syncthreads();
    for (int s = 128; s > 0; s >>= 1) {
        if (t < s) red[t] += red[t + s];
        __syncthreads();
    }
    float scale = rsqrtf(red[0] / 512.f + 1e-6f);

    const float SF = 0.17677669529663687f;   // 1/sqrt(32)
    {
        int h = t >> 5, j = t & 31;
        size_t qb = ((size_t)(b * 8 + h) * NW + n) * 64;
        qcat[qb + j] = f2bf(o1 * scale * fqk_g[t] * SF);
        kcat[qb + j] = f2bf(o2 * scale * fqk_g[t + 256]);
    }
    __syncthreads();

    float co = 0.f;
    if (t < 128) {
        co = cqk_b[t];
        #pragma unroll
        for (int k = 0; k < 4; ++k) co += cavg[k] * cqk_w[t * 4 + k];
    }
    red[t] = (t < 128) ? co * co : 0.f;
    __syncthreads();
    for (int s = 128; s > 0; s >>= 1) {
        if (t < s) red[t] += red[t + s];
        __syncthreads();
    }
    float cscale = rsqrtf(red[0] / 128.f + 1e-6f);

    const float SC = 0.35355339059327373f;   // 1/sqrt(8)
    if (t < 64) {
        int h = t >> 3, j = 32 + (t & 7);
        qcat[((size_t)(b * 8 + h) * NW + n) * 64 + j] = f2bf(co * cscale * cqk_g[t] * SC);
    } else if (t < 128) {
        int tt = t - 64;
        int h = tt >> 3, j = 32 + (tt & 7);
        kcat[((size_t)(b * 8 + h) * NW + n) * 64 + j] = f2bf(co * cscale * cqk_g[t]);
    } else {
        int tt = t - 128;
        for (int z = tt; z < 384; z += 128) {
            int which = z & 1;
            int zz = z >> 1;
            int h = zz / 24, j = 40 + zz % 24;
            short* dst = which ? kcat : qcat;
            dst[((size_t)(b * 8 + h) * NW + n) * 64 + j] = 0;
        }
    }
}

// ---------------------------------------------------------------------------
// scores v2: swapped-operand MFMA. Wave computes S^T tile: D[m][n]=k_m . q_n
// over its quadrant's m-tiles, softmax over m in-register (+2 shfl_xor).
// ---------------------------------------------------------------------------
template <int NMT>
static __device__ __forceinline__ void scores_wave(const short* __restrict__ qcat,
                                                   const short* __restrict__ kcat,
                                                   short* __restrict__ Pb,
                                                   int b, int h, int n0, int mbase, int lane) {
    int l15 = lane & 15, g = lane >> 4;
    int kl8 = g * 8;
    size_t rowb = (size_t)(b * 8 + h) * NW;

    const short* qrow = qcat + (rowb + n0 + l15) * 64;
    short8v bf0 = *(const short8v*)(qrow + kl8);
    short8v bf1 = *(const short8v*)(qrow + 32 + kl8);

    f32x4 acc[NMT];
    #pragma unroll
    for (int i = 0; i < NMT; ++i) acc[i] = (f32x4)0.f;

    #pragma unroll
    for (int mt = 0; mt < NMT; ++mt) {
        const short* krow = kcat + (rowb + mbase + mt * 16 + l15) * 64;
        short8v af0 = *(const short8v*)(krow + kl8);
        short8v af1 = *(const short8v*)(krow + 32 + kl8);
        acc[mt] = __builtin_amdgcn_mfma_f32_16x16x32_bf16(af0, bf0, acc[mt], 0, 0, 0);
        acc[mt] = __builtin_amdgcn_mfma_f32_16x16x32_bf16(af1, bf1, acc[mt], 0, 0, 0);
    }

    float mx = -3.4e38f;
    #pragma unroll
    for (int mt = 0; mt < NMT; ++mt)
        #pragma unroll
        for (int r = 0; r < 4; ++r) mx = fmaxf(mx, acc[mt][r]);
    mx = fmaxf(mx, __shfl_xor(mx, 16, 64));
    mx = fmaxf(mx, __shfl_xor(mx, 32, 64));

    float sum = 0.f;
    #pragma unroll
    for (int mt = 0; mt < NMT; ++mt)
        #pragma unroll
        for (int r = 0; r < 4; ++r) {
            float e = __expf(acc[mt][r] - mx);
            acc[mt][r] = e;
            sum += e;
        }
    sum += __shfl_xor(sum, 16, 64);
    sum += __shfl_xor(sum, 32, 64);
    float inv = 1.f / sum;

    int n = n0 + l15;
    short* prow = Pb + ((size_t)(b * 8 + h) * 512 + n) * 416;
    #pragma unroll
    for (int mt = 0; mt < NMT; ++mt) {
        int m = mbase + mt * 16 + g * 4;
        *(short4*)(prow + m) = make_short4(f2bf(acc[mt][0] * inv), f2bf(acc[mt][1] * inv),
                                           f2bf(acc[mt][2] * inv), f2bf(acc[mt][3] * inv));
    }
}

__global__ __launch_bounds__(256) void scores_kernel(const short* __restrict__ qcat,
                                                     const short* __restrict__ kcat,
                                                     short* __restrict__ Pb) {
    int wid = blockIdx.x * 4 + (threadIdx.x >> 6);
    int lane = threadIdx.x & 63;
    if (wid < 512) {
        int b = wid >> 7, h = (wid >> 4) & 7, n0 = (wid & 15) * 16;
        scores_wave<9>(qcat, kcat, Pb, b, h, n0, 256, lane);
    } else {
        int t3 = wid - 512;
        int b = t3 / 72, r = t3 % 72;
        int h = r / 9, n0 = 256 + (r % 9) * 16;
        scores_wave<16>(qcat, kcat, Pb, b, h, n0, 0, lane);
    }
}

// ---------------------------------------------------------------------------
// wproj v2: Wb[R][d] = Xw[R][:] . M[d][:], all-bf16.
// grid: rt400 x rh2 x dt2 = 1600 blocks. Block = 128d x 128R, 4 waves 2x2.
// Xw3 k-chunks staged reg->LDS (80B padded rows, conflict-free), Mbf coalesced.
// ---------------------------------------------------------------------------
__global__ __launch_bounds__(256, 2) void wproj_mfma(const short* __restrict__ Xw3,
                                                     const short* __restrict__ Mbf,
                                                     short* __restrict__ Wb) {
    int bid = blockIdx.x;
    int dt = bid & 1, rh = (bid >> 1) & 1, rt = bid >> 2;
    int tid = threadIdx.x;
    int lane = tid & 63, w = tid >> 6;
    int wd = w & 1, wrR = w >> 1;
    int l15 = lane & 15, g = lane >> 4;

    __shared__ short lds[2][128][40];

    int idx0 = tid, idx1 = tid + 256;
    int R0 = idx0 >> 2, c0 = idx0 & 3;
    int R1 = idx1 >> 2, c1 = idx1 & 3;

    short8v st0, st1;
    {
        const short* s = Xw3 + (((size_t)rt * 8 + 0) * 256 + rh * 128) * 32;
        st0 = *(const short8v*)(s + idx0 * 8);
        st1 = *(const short8v*)(s + idx1 * 8);
    }

    f32x4 acc[4][4] = {};
    for (int kc = 0; kc < 8; ++kc) {
        int buf = kc & 1;
        *(short8v*)&lds[buf][R0][c0 * 8] = st0;
        *(short8v*)&lds[buf][R1][c1 * 8] = st1;
        if (kc < 7) {
            const short* s = Xw3 + (((size_t)rt * 8 + kc + 1) * 256 + rh * 128) * 32;
            st0 = *(const short8v*)(s + idx0 * 8);
            st1 = *(const short8v*)(s + idx1 * 8);
        }
        short8v af[4];
        #pragma unroll
        for (int mi = 0; mi < 4; ++mi) {
            int dtile = dt * 8 + wd * 4 + mi;
            af[mi] = *(const short8v*)(Mbf + ((size_t)(dtile * 8 + kc)) * 512 + lane * 8);
        }
        __syncthreads();
        #pragma unroll
        for (int ni = 0; ni < 4; ++ni) {
            int Rl = wrR * 64 + ni * 16 + l15;
            short8v bf = *(const short8v*)&lds[buf][Rl][g * 8];
            #pragma unroll
            for (int mi = 0; mi < 4; ++mi)
                acc[mi][ni] = __builtin_amdgcn_mfma_f32_16x16x32_bf16(af[mi], bf, acc[mi][ni], 0, 0, 0);
        }
    }

    int dq = dt * 128 + wd * 64 + g * 4;
    #pragma unroll
    for (int ni = 0; ni < 4; ++ni) {
        size_t Rg = (size_t)rt * 256 + rh * 128 + wrR * 64 + ni * 16 + l15;
        short* wp = Wb + Rg * 256 + dq;
        #pragma unroll
        for (int mi = 0; mi < 4; ++mi) {
            f32x4 a = acc[mi][ni];
            *(short4*)(wp + mi * 16) = make_short4(f2bf(a[0]), f2bf(a[1]), f2bf(a[2]), f2bf(a[3]));
        }
    }
}

// ---------------------------------------------------------------------------
// pv: A = Pb rows (m-contiguous), B = Wb staged to LDS (tr-subtiled),
// read via ds_read_b64_tr_b16. Block 128n x 128d, 4 waves 2x2.
// ---------------------------------------------------------------------------
__global__ __launch_bounds__(256, 2) void pv_mfma(
    const short* __restrict__ Pb, const short* __restrict__ Wb,
    float* __restrict__ out) {
    int bid = blockIdx.x;
    int dt = bid & 1;
    int nt = (bid >> 1) & 3;
    int p  = (bid >> 3) & 63;
    int b  = bid >> 9;
    int h  = p >> 3;
    int tid = threadIdx.x;
    int lane = tid & 63;
    int w = tid >> 6;
    int wr = w >> 1;
    int wc = w & 1;
    int l15 = lane & 15;
    int kl8 = (lane >> 4) << 3;

    __shared__ short8v Bs[512];
    unsigned ldsBase = (unsigned)(size_t)&Bs[0];

    int n0 = nt * 128;
    int mlo = (nt < 2) ? 256 : 0;
    int mhi = (nt < 2) ? 400 : 256;
    int d0 = dt * 128;

    const short* arow[4];
    #pragma unroll
    for (int mi = 0; mi < 4; ++mi) {
        int n = n0 + wr * 64 + mi * 16 + l15;
        arow[mi] = Pb + ((size_t)(b * 8 + h) * 512 + n) * 416 + kl8;
    }

    f32x4 acc[4][4] = {};

    int mrow0 = tid >> 4;
    int doff0 = (tid & 15) << 3;
    int mrow1 = (tid + 256) >> 4;
    int doff1 = doff0;

    const size_t wbBase = ((size_t)b * 400) * 64 * 256 + (size_t)p * 256 + d0;

    short8v cur0, cur1;
    {
        int gm0 = mlo + mrow0, gm1 = mlo + mrow1;
        cur0 = (gm0 < mhi) ? *(const short8v*)(Wb + wbBase + (size_t)gm0 * 64 * 256 + doff0) : (short8v)0;
        cur1 = (gm1 < mhi) ? *(const short8v*)(Wb + wbBase + (size_t)gm1 * 64 * 256 + doff1) : (short8v)0;
    }

    for (int m0 = mlo; m0 < mhi; m0 += 32) {
        short8v af[4];
        #pragma unroll
        for (int mi = 0; mi < 4; ++mi)
            af[mi] = *(const short8v*)(arow[mi] + m0);

        __syncthreads();
        {
            int par = (mrow0 >> 2) & 1, gg = mrow0 >> 3, r = mrow0 & 3;
            int nb = doff0 >> 4, c0h = (doff0 >> 3) & 1;
            Bs[(par * 8 + nb) * 32 + gg * 8 + r * 2 + c0h] = cur0;
            par = (mrow1 >> 2) & 1; gg = mrow1 >> 3; r = mrow1 & 3;
            nb = doff1 >> 4; c0h = (doff1 >> 3) & 1;
            Bs[(par * 8 + nb) * 32 + gg * 8 + r * 2 + c0h] = cur1;
        }
        if (m0 + 32 < mhi) {
            int gm0 = m0 + 32 + mrow0, gm1 = m0 + 32 + mrow1;
            cur0 = (gm0 < mhi) ? *(const short8v*)(Wb + wbBase + (size_t)gm0 * 64 * 256 + doff0) : (short8v)0;
            cur1 = (gm1 < mhi) ? *(const short8v*)(Wb + wbBase + (size_t)gm1 * 64 * 256 + doff1) : (short8v)0;
        }
        __syncthreads();

        short8v bf[4];
        #pragma unroll
        for (int ni = 0; ni < 4; ++ni) {
            int nb = wc * 4 + ni;
            unsigned a0 = ldsBase + (unsigned)((0 * 8 + nb) * 512 + lane * 8);
            unsigned a1 = ldsBase + (unsigned)((1 * 8 + nb) * 512 + lane * 8);
            uint2v lo, hi;
            asm volatile("ds_read_b64_tr_b16 %0, %1" : "=v"(lo) : "v"(a0));
            asm volatile("ds_read_b64_tr_b16 %0, %1" : "=v"(hi) : "v"(a1));
            uint4v bw; bw.x = lo.x; bw.y = lo.y; bw.z = hi.x; bw.w = hi.y;
            bf[ni] = __builtin_bit_cast(short8v, bw);
        }
        asm volatile("s_waitcnt lgkmcnt(0)" ::: "memory");
        __builtin_amdgcn_sched_barrier(0);

        #pragma unroll
        for (int mi = 0; mi < 4; ++mi) {
            #pragma unroll
            for (int ni = 0; ni < 4; ++ni)
                acc[mi][ni] = __builtin_amdgcn_mfma_f32_16x16x32_bf16(af[mi], bf[ni], acc[mi][ni], 0, 0, 0);
        }
    }

    int pr = p >> 3, pc = p & 7;
    #pragma unroll
    for (int mi = 0; mi < 4; ++mi) {
        #pragma unroll
        for (int r = 0; r < 4; ++r) {
            int n = n0 + wr * 64 + mi * 16 + ((lane >> 4) << 2) + r;
            if (n >= NW) continue;
            float* obase;
            if (n < N1) {
                obase = out + (((size_t)b * 128 + (n >> 4) * 8 + pr) * 128 + ((n & 15) << 3) + pc) * 256;
            } else {
                int nn = n - N1;
                obase = out + OUT2_OFF + (((size_t)b * 96 + (nn / 12) * 8 + pr) * 96 + (nn % 12) * 8 + pc) * 256;
            }
            #pragma unroll
            for (int ni = 0; ni < 4; ++ni)
                obase[d0 + wc * 64 + ni * 16 + l15] = acc[mi][ni][r];
        }
    }
}

// ---------------------------------------------------------------------------
extern "C" void kernel_launch(void* const* d_in, const int* in_sizes, int n_in,
                              void* d_out, int out_size, void* d_ws, size_t ws_size,
                              hipStream_t stream) {
    const float* x1    = (const float*)d_in[0];
    const float* c1    = (const float*)d_in[1];
    const float* x2    = (const float*)d_in[2];
    const float* c2    = (const float*)d_in[3];
    const float* fqk_w = (const float*)d_in[4];
    const float* fqk_b = (const float*)d_in[5];
    const float* fqk_g = (const float*)d_in[6];
    const float* cqk_w = (const float*)d_in[7];
    const float* cqk_b = (const float*)d_in[8];
    const float* cqk_g = (const float*)d_in[9];
    const float* v_w   = (const float*)d_in[10];
    const float* vb_w  = (const float*)d_in[11];
    float* out = (float*)d_out;

    char* wsb = (char*)d_ws;
    short* Mbf    = (short*)(wsb);                    //     131,072 B (256*256*2 — was 64KB: NaN bug)
    float* fqk_wT = (float*)(wsb + 131072);           //     524,288 B
    short* qcat   = (short*)(wsb + 655360);           //   1,638,400 B
    short* kcat   = (short*)(wsb + 2293760);          //   1,638,400 B
    short* Pb     = (short*)(wsb + 3932160);          //  13,631,488 B
    short* Xw3    = (short*)(wsb + 17563648);         //  52,428,800 B
    short* Wb     = (short*)(wsb + 69992448);         //  52,428,800 B (ends 122,421,248)

    prep_kernel<<<256, 256, 0, stream>>>(v_w, vb_w, Mbf);
    transpose_fqk<<<512, 256, 0, stream>>>(fqk_w, fqk_wT);
    stage1_kernel<<<B * NW, 256, 0, stream>>>(x1, c1, x2, c2, fqk_wT, fqk_b, fqk_g,
                                              cqk_w, cqk_b, cqk_g, qcat, kcat, Xw3);
    wproj_mfma<<<1600, 256, 0, stream>>>(Xw3, Mbf, Wb);
    scores_kernel<<<200, 256, 0, stream>>>(qcat, kcat, Pb);
    pv_mfma<<<2048, 256, 0, stream>>>(Pb, Wb, out);
}

// Round 7
// 343.151 us; speedup vs baseline: 1.9269x; 1.0289x over previous
//
#include <hip/hip_runtime.h>
#include <hip/hip_bf16.h>

#define B 4
#define NH 8
#define N1 256
#define N2 144
#define NW 400
#define OUT2_OFF ((size_t)16777216)   // 4*128*128*256

typedef __attribute__((ext_vector_type(8))) short short8v;
typedef __attribute__((ext_vector_type(4))) float f32x4;
typedef __attribute__((ext_vector_type(2))) unsigned uint2v;
typedef __attribute__((ext_vector_type(4))) unsigned uint4v;

static __device__ __forceinline__ short f2bf(float f) {
    __hip_bfloat16 h = __float2bfloat16(f);
    return __builtin_bit_cast(short, h);
}

// row base for (window n, pixel p), channel 0
static __device__ __forceinline__ const float* xrow_ptr(const float* x1, const float* x2,
                                                        int b, int n, int p) {
    if (n < N1)
        return x1 + (((size_t)b * 128 + (n >> 4) * 8 + (p >> 3)) * 128 + (n & 15) * 8 + (p & 7)) * 256;
    int nn = n - N1;
    return x2 + (((size_t)b * 96 + (nn / 12) * 8 + (p >> 3)) * 96 + (nn % 12) * 8 + (p & 7)) * 256;
}

// ---------------------------------------------------------------------------
// prep: M = vb_w @ v_w fused (256x256), stored in MFMA-A-frag order:
// Mbf[(dtile*8 + kc)*512 + kgrp*128 + (d&15)*8 + (k&7)] -> af load = base + lane*8.
// Mbf spans 131072 BYTES.
// ---------------------------------------------------------------------------
__global__ void prep_kernel(const float* __restrict__ v_w, const float* __restrict__ vb_w,
                            short* __restrict__ Mbf) {
    int d = blockIdx.x;
    int k = threadIdx.x;
    float s = 0.f;
    for (int j = 0; j < 256; ++j)
        s += vb_w[d * 256 + j] * v_w[j * 256 + k];
    size_t idx = ((((size_t)((d >> 4) * 8 + (k >> 5))) * 4 + ((k >> 3) & 3)) * 16 + (d & 15)) * 8 + (k & 7);
    Mbf[idx] = f2bf(s);
}

// fqk_w (512x256 fp32) -> bf16 row-major (A-frag source for qkproj)
__global__ void wconv_kernel(const float* __restrict__ fqk_w, short* __restrict__ fqk_wb) {
    int i = blockIdx.x * 256 + threadIdx.x;
    fqk_wb[i] = f2bf(fqk_w[i]);
}

// ---------------------------------------------------------------------------
// mean_kernel: per (b,n): favgb bf16 row (256), coord avg + coord QK proj + RMS,
// writes qcat/kcat j=32..39 (+ zero-fill j=40..63). grid 1600, block 256.
// ---------------------------------------------------------------------------
__global__ void mean_kernel(const float* __restrict__ x1, const float* __restrict__ c1,
                            const float* __restrict__ x2, const float* __restrict__ c2,
                            const float* __restrict__ cqk_w, const float* __restrict__ cqk_b,
                            const float* __restrict__ cqk_g,
                            short* __restrict__ favgb,
                            short* __restrict__ qcat, short* __restrict__ kcat) {
    int blk = blockIdx.x;
    int b = blk / NW, n = blk % NW;
    int t = threadIdx.x;

    __shared__ float cavg[4];
    __shared__ float red[256];

    const float* xbase;
    int rstride;
    if (n < N1) {
        xbase = x1 + (((size_t)b * 128 + (n >> 4) * 8) * 128 + (n & 15) * 8) * 256;
        rstride = 128 * 256;
    } else {
        int nn = n - N1;
        xbase = x2 + (((size_t)b * 96 + (nn / 12) * 8) * 96 + (nn % 12) * 8) * 256;
        rstride = 96 * 256;
    }

    float a0 = 0.f, a1 = 0.f, a2 = 0.f, a3 = 0.f;
    #pragma unroll
    for (int pr = 0; pr < 8; ++pr) {
        const float* rowp = xbase + (size_t)pr * rstride + t;
        a0 += rowp[0 * 256] + rowp[4 * 256];
        a1 += rowp[1 * 256] + rowp[5 * 256];
        a2 += rowp[2 * 256] + rowp[6 * 256];
        a3 += rowp[3 * 256] + rowp[7 * 256];
    }
    favgb[(size_t)blk * 256 + t] = f2bf((a0 + a1 + a2 + a3) * (1.f / 64.f));

    if (t < 64) {
        const float* cbase;
        int crs;
        if (n < N1) {
            cbase = c1 + (((size_t)b * 128 + (n >> 4) * 8) * 128 + (n & 15) * 8) * 4;
            crs = 128 * 4;
        } else {
            int nn = n - N1;
            cbase = c2 + (((size_t)b * 96 + (nn / 12) * 8) * 96 + (nn % 12) * 8) * 4;
            crs = 96 * 4;
        }
        float4 v = *(const float4*)(cbase + (t >> 3) * crs + (t & 7) * 4);
        for (int off = 32; off > 0; off >>= 1) {
            v.x += __shfl_down(v.x, off, 64);
            v.y += __shfl_down(v.y, off, 64);
            v.z += __shfl_down(v.z, off, 64);
            v.w += __shfl_down(v.w, off, 64);
        }
        if (t == 0) {
            cavg[0] = v.x * (1.f / 64.f);
            cavg[1] = v.y * (1.f / 64.f);
            cavg[2] = v.z * (1.f / 64.f);
            cavg[3] = v.w * (1.f / 64.f);
        }
    }
    __syncthreads();

    float co = 0.f;
    if (t < 128) {
        co = cqk_b[t];
        #pragma unroll
        for (int k = 0; k < 4; ++k) co += cavg[k] * cqk_w[t * 4 + k];
    }
    red[t] = (t < 128) ? co * co : 0.f;
    __syncthreads();
    for (int s = 128; s > 0; s >>= 1) {
        if (t < s) red[t] += red[t + s];
        __syncthreads();
    }
    float cscale = rsqrtf(red[0] / 128.f + 1e-6f);

    const float SC = 0.35355339059327373f;   // 1/sqrt(8)
    if (t < 64) {
        int h = t >> 3, j = 32 + (t & 7);
        qcat[((size_t)(b * 8 + h) * NW + n) * 64 + j] = f2bf(co * cscale * cqk_g[t] * SC);
    } else if (t < 128) {
        int tt = t - 64;
        int h = tt >> 3, j = 32 + (tt & 7);
        kcat[((size_t)(b * 8 + h) * NW + n) * 64 + j] = f2bf(co * cscale * cqk_g[t]);
    } else {
        int tt = t - 128;
        for (int z = tt; z < 384; z += 128) {
            int which = z & 1;
            int zz = z >> 1;
            int h = zz / 24, j = 40 + zz % 24;
            short* dst = which ? kcat : qcat;
            dst[((size_t)(b * 8 + h) * NW + n) * 64 + j] = 0;
        }
    }
}

// ---------------------------------------------------------------------------
// qkproj: MFMA GEMM D[o][n] = sum_k fqk_w[o][k]*favg[n][k], + bias, RMS(512),
// scaled bf16 writes into qcat (o<256, with 1/sqrt(32)) / kcat (o>=256).
// wave = (n-group of 16) x (o-half of 256). block = 2 n-groups x 2 halves.
// grid 50 blocks.
// ---------------------------------------------------------------------------
__global__ __launch_bounds__(256) void qkproj_kernel(const short* __restrict__ fqk_wb,
                                                     const float* __restrict__ fqk_b,
                                                     const float* __restrict__ fqk_g,
                                                     const short* __restrict__ favgb,
                                                     short* __restrict__ qcat,
                                                     short* __restrict__ kcat) {
    int w = threadIdx.x >> 6, lane = threadIdx.x & 63;
    int ngl = w >> 1, half = w & 1;
    int ngrp = blockIdx.x * 2 + ngl;
    int l15 = lane & 15, g = lane >> 4;

    __shared__ float ssb[2][2][16];

    const short* frow = favgb + ((size_t)ngrp * 16 + l15) * 256;
    short8v bf[8];
    #pragma unroll
    for (int c = 0; c < 8; ++c) bf[c] = *(const short8v*)(frow + c * 32 + g * 8);

    f32x4 acc[16];
    #pragma unroll
    for (int i = 0; i < 16; ++i) acc[i] = (f32x4)0.f;

    #pragma unroll
    for (int mt = 0; mt < 16; ++mt) {
        const short* arow = fqk_wb + ((size_t)(half * 256 + mt * 16 + l15)) * 256;
        #pragma unroll
        for (int c = 0; c < 8; ++c) {
            short8v af = *(const short8v*)(arow + c * 32 + g * 8);
            acc[mt] = __builtin_amdgcn_mfma_f32_16x16x32_bf16(af, bf[c], acc[mt], 0, 0, 0);
        }
    }

    // + bias, sum of squares (this lane holds o = half*256 + mt*16 + g*4 + r, n = ngrp*16+l15)
    float ss = 0.f;
    #pragma unroll
    for (int mt = 0; mt < 16; ++mt) {
        float4 bi = *(const float4*)(fqk_b + half * 256 + mt * 16 + g * 4);
        acc[mt][0] += bi.x; acc[mt][1] += bi.y; acc[mt][2] += bi.z; acc[mt][3] += bi.w;
        ss += acc[mt][0] * acc[mt][0] + acc[mt][1] * acc[mt][1]
            + acc[mt][2] * acc[mt][2] + acc[mt][3] * acc[mt][3];
    }
    ss += __shfl_xor(ss, 16, 64);
    ss += __shfl_xor(ss, 32, 64);
    if (lane < 16) ssb[ngl][half][lane] = ss;
    __syncthreads();
    float scale = rsqrtf((ssb[ngl][0][l15] + ssb[ngl][1][l15]) / 512.f + 1e-6f);

    int idx = ngrp * 16 + l15;
    int b = idx / NW, n = idx % NW;
    const float SF = 0.17677669529663687f;   // 1/sqrt(32), folded into q
    float mult = half ? 1.f : SF;
    short* dst = half ? kcat : qcat;

    #pragma unroll
    for (int mt = 0; mt < 16; ++mt) {
        int ol = mt * 16 + g * 4;                 // 0..255 within half
        float4 gg = *(const float4*)(fqk_g + half * 256 + ol);
        int h = ol >> 5, j = ol & 31;
        short4 s4 = make_short4(f2bf(acc[mt][0] * scale * gg.x * mult),
                                f2bf(acc[mt][1] * scale * gg.y * mult),
                                f2bf(acc[mt][2] * scale * gg.z * mult),
                                f2bf(acc[mt][3] * scale * gg.w * mult));
        *(short4*)(dst + ((size_t)(b * 8 + h) * NW + n) * 64 + j) = s4;
    }
}

// ---------------------------------------------------------------------------
// scores: swapped-operand MFMA, softmax over m in-register. (unchanged)
// ---------------------------------------------------------------------------
template <int NMT>
static __device__ __forceinline__ void scores_wave(const short* __restrict__ qcat,
                                                   const short* __restrict__ kcat,
                                                   short* __restrict__ Pb,
                                                   int b, int h, int n0, int mbase, int lane) {
    int l15 = lane & 15, g = lane >> 4;
    int kl8 = g * 8;
    size_t rowb = (size_t)(b * 8 + h) * NW;

    const short* qrow = qcat + (rowb + n0 + l15) * 64;
    short8v bf0 = *(const short8v*)(qrow + kl8);
    short8v bf1 = *(const short8v*)(qrow + 32 + kl8);

    f32x4 acc[NMT];
    #pragma unroll
    for (int i = 0; i < NMT; ++i) acc[i] = (f32x4)0.f;

    #pragma unroll
    for (int mt = 0; mt < NMT; ++mt) {
        const short* krow = kcat + (rowb + mbase + mt * 16 + l15) * 64;
        short8v af0 = *(const short8v*)(krow + kl8);
        short8v af1 = *(const short8v*)(krow + 32 + kl8);
        acc[mt] = __builtin_amdgcn_mfma_f32_16x16x32_bf16(af0, bf0, acc[mt], 0, 0, 0);
        acc[mt] = __builtin_amdgcn_mfma_f32_16x16x32_bf16(af1, bf1, acc[mt], 0, 0, 0);
    }

    float mx = -3.4e38f;
    #pragma unroll
    for (int mt = 0; mt < NMT; ++mt)
        #pragma unroll
        for (int r = 0; r < 4; ++r) mx = fmaxf(mx, acc[mt][r]);
    mx = fmaxf(mx, __shfl_xor(mx, 16, 64));
    mx = fmaxf(mx, __shfl_xor(mx, 32, 64));

    float sum = 0.f;
    #pragma unroll
    for (int mt = 0; mt < NMT; ++mt)
        #pragma unroll
        for (int r = 0; r < 4; ++r) {
            float e = __expf(acc[mt][r] - mx);
            acc[mt][r] = e;
            sum += e;
        }
    sum += __shfl_xor(sum, 16, 64);
    sum += __shfl_xor(sum, 32, 64);
    float inv = 1.f / sum;

    int n = n0 + l15;
    short* prow = Pb + ((size_t)(b * 8 + h) * 512 + n) * 416;
    #pragma unroll
    for (int mt = 0; mt < NMT; ++mt) {
        int m = mbase + mt * 16 + g * 4;
        *(short4*)(prow + m) = make_short4(f2bf(acc[mt][0] * inv), f2bf(acc[mt][1] * inv),
                                           f2bf(acc[mt][2] * inv), f2bf(acc[mt][3] * inv));
    }
}

__global__ __launch_bounds__(256) void scores_kernel(const short* __restrict__ qcat,
                                                     const short* __restrict__ kcat,
                                                     short* __restrict__ Pb) {
    int wid = blockIdx.x * 4 + (threadIdx.x >> 6);
    int lane = threadIdx.x & 63;
    if (wid < 512) {
        int b = wid >> 7, h = (wid >> 4) & 7, n0 = (wid & 15) * 16;
        scores_wave<9>(qcat, kcat, Pb, b, h, n0, 256, lane);
    } else {
        int t3 = wid - 512;
        int b = t3 / 72, r = t3 % 72;
        int h = r / 9, n0 = 256 + (r % 9) * 16;
        scores_wave<16>(qcat, kcat, Pb, b, h, n0, 0, lane);
    }
}

// ---------------------------------------------------------------------------
// wproj v3: Wb[R][d] = X[R][:].M[d][:], staging X DIRECTLY from global fp32
// (cvt in regs, LDS [2][128][40]), Mbf coalesced A-frags. No Xw3.
// grid rt400 x rh2 x dt2 = 1600 blocks, 4 waves 2x2.
// ---------------------------------------------------------------------------
__global__ __launch_bounds__(256, 2) void wproj_mfma(const float* __restrict__ x1,
                                                     const float* __restrict__ x2,
                                                     const short* __restrict__ Mbf,
                                                     short* __restrict__ Wb) {
    int bid = blockIdx.x;
    int dt = bid & 1, rh = (bid >> 1) & 1, rt = bid >> 2;
    int tid = threadIdx.x;
    int lane = tid & 63, w = tid >> 6;
    int wd = w & 1, wrR = w >> 1;
    int l15 = lane & 15, g = lane >> 4;

    __shared__ short lds[2][128][40];

    int b = rt / 100;
    int nb0 = (rt % 100) * 4 + rh * 2;

    int Rl0 = tid >> 2, oc = tid & 3;    // item0: rows 0..63
    int Rl1 = Rl0 + 64;                  // item1: rows 64..127
    const float* src0 = xrow_ptr(x1, x2, b, nb0 + (Rl0 >> 6), Rl0 & 63) + oc * 8;
    const float* src1 = xrow_ptr(x1, x2, b, nb0 + (Rl1 >> 6), Rl1 & 63) + oc * 8;

    float4 p00 = *(const float4*)(src0);
    float4 p01 = *(const float4*)(src0 + 4);
    float4 p10 = *(const float4*)(src1);
    float4 p11 = *(const float4*)(src1 + 4);

    f32x4 acc[4][4] = {};
    for (int kc = 0; kc < 8; ++kc) {
        int buf = kc & 1;
        short8v s0, s1;
        s0[0] = f2bf(p00.x); s0[1] = f2bf(p00.y); s0[2] = f2bf(p00.z); s0[3] = f2bf(p00.w);
        s0[4] = f2bf(p01.x); s0[5] = f2bf(p01.y); s0[6] = f2bf(p01.z); s0[7] = f2bf(p01.w);
        s1[0] = f2bf(p10.x); s1[1] = f2bf(p10.y); s1[2] = f2bf(p10.z); s1[3] = f2bf(p10.w);
        s1[4] = f2bf(p11.x); s1[5] = f2bf(p11.y); s1[6] = f2bf(p11.z); s1[7] = f2bf(p11.w);
        *(short8v*)&lds[buf][Rl0][oc * 8] = s0;
        *(short8v*)&lds[buf][Rl1][oc * 8] = s1;
        if (kc < 7) {
            const float* q0 = src0 + (kc + 1) * 32;
            const float* q1 = src1 + (kc + 1) * 32;
            p00 = *(const float4*)q0; p01 = *(const float4*)(q0 + 4);
            p10 = *(const float4*)q1; p11 = *(const float4*)(q1 + 4);
        }
        short8v af[4];
        #pragma unroll
        for (int mi = 0; mi < 4; ++mi) {
            int dtile = dt * 8 + wd * 4 + mi;
            af[mi] = *(const short8v*)(Mbf + ((size_t)(dtile * 8 + kc)) * 512 + lane * 8);
        }
        __syncthreads();
        #pragma unroll
        for (int ni = 0; ni < 4; ++ni) {
            int Rl = wrR * 64 + ni * 16 + l15;
            short8v bfv = *(const short8v*)&lds[buf][Rl][g * 8];
            #pragma unroll
            for (int mi = 0; mi < 4; ++mi)
                acc[mi][ni] = __builtin_amdgcn_mfma_f32_16x16x32_bf16(af[mi], bfv, acc[mi][ni], 0, 0, 0);
        }
    }

    int dq = dt * 128 + wd * 64 + g * 4;
    #pragma unroll
    for (int ni = 0; ni < 4; ++ni) {
        size_t Rg = (size_t)rt * 256 + rh * 128 + wrR * 64 + ni * 16 + l15;
        short* wp = Wb + Rg * 256 + dq;
        #pragma unroll
        for (int mi = 0; mi < 4; ++mi) {
            f32x4 a = acc[mi][ni];
            *(short4*)(wp + mi * 16) = make_short4(f2bf(a[0]), f2bf(a[1]), f2bf(a[2]), f2bf(a[3]));
        }
    }
}

// ---------------------------------------------------------------------------
// pv: unchanged.
// ---------------------------------------------------------------------------
__global__ __launch_bounds__(256, 2) void pv_mfma(
    const short* __restrict__ Pb, const short* __restrict__ Wb,
    float* __restrict__ out) {
    int bid = blockIdx.x;
    int dt = bid & 1;
    int nt = (bid >> 1) & 3;
    int p  = (bid >> 3) & 63;
    int b  = bid >> 9;
    int h  = p >> 3;
    int tid = threadIdx.x;
    int lane = tid & 63;
    int w = tid >> 6;
    int wr = w >> 1;
    int wc = w & 1;
    int l15 = lane & 15;
    int kl8 = (lane >> 4) << 3;

    __shared__ short8v Bs[512];
    unsigned ldsBase = (unsigned)(size_t)&Bs[0];

    int n0 = nt * 128;
    int mlo = (nt < 2) ? 256 : 0;
    int mhi = (nt < 2) ? 400 : 256;
    int d0 = dt * 128;

    const short* arow[4];
    #pragma unroll
    for (int mi = 0; mi < 4; ++mi) {
        int n = n0 + wr * 64 + mi * 16 + l15;
        arow[mi] = Pb + ((size_t)(b * 8 + h) * 512 + n) * 416 + kl8;
    }

    f32x4 acc[4][4] = {};

    int mrow0 = tid >> 4;
    int doff0 = (tid & 15) << 3;
    int mrow1 = (tid + 256) >> 4;
    int doff1 = doff0;

    const size_t wbBase = ((size_t)b * 400) * 64 * 256 + (size_t)p * 256 + d0;

    short8v cur0, cur1;
    {
        int gm0 = mlo + mrow0, gm1 = mlo + mrow1;
        cur0 = (gm0 < mhi) ? *(const short8v*)(Wb + wbBase + (size_t)gm0 * 64 * 256 + doff0) : (short8v)0;
        cur1 = (gm1 < mhi) ? *(const short8v*)(Wb + wbBase + (size_t)gm1 * 64 * 256 + doff1) : (short8v)0;
    }

    for (int m0 = mlo; m0 < mhi; m0 += 32) {
        short8v af[4];
        #pragma unroll
        for (int mi = 0; mi < 4; ++mi)
            af[mi] = *(const short8v*)(arow[mi] + m0);

        __syncthreads();
        {
            int par = (mrow0 >> 2) & 1, gg = mrow0 >> 3, r = mrow0 & 3;
            int nb = doff0 >> 4, c0h = (doff0 >> 3) & 1;
            Bs[(par * 8 + nb) * 32 + gg * 8 + r * 2 + c0h] = cur0;
            par = (mrow1 >> 2) & 1; gg = mrow1 >> 3; r = mrow1 & 3;
            nb = doff1 >> 4; c0h = (doff1 >> 3) & 1;
            Bs[(par * 8 + nb) * 32 + gg * 8 + r * 2 + c0h] = cur1;
        }
        if (m0 + 32 < mhi) {
            int gm0 = m0 + 32 + mrow0, gm1 = m0 + 32 + mrow1;
            cur0 = (gm0 < mhi) ? *(const short8v*)(Wb + wbBase + (size_t)gm0 * 64 * 256 + doff0) : (short8v)0;
            cur1 = (gm1 < mhi) ? *(const short8v*)(Wb + wbBase + (size_t)gm1 * 64 * 256 + doff1) : (short8v)0;
        }
        __syncthreads();

        short8v bfv[4];
        #pragma unroll
        for (int ni = 0; ni < 4; ++ni) {
            int nb = wc * 4 + ni;
            unsigned a0 = ldsBase + (unsigned)((0 * 8 + nb) * 512 + lane * 8);
            unsigned a1 = ldsBase + (unsigned)((1 * 8 + nb) * 512 + lane * 8);
            uint2v lo, hi;
            asm volatile("ds_read_b64_tr_b16 %0, %1" : "=v"(lo) : "v"(a0));
            asm volatile("ds_read_b64_tr_b16 %0, %1" : "=v"(hi) : "v"(a1));
            uint4v bw; bw.x = lo.x; bw.y = lo.y; bw.z = hi.x; bw.w = hi.y;
            bfv[ni] = __builtin_bit_cast(short8v, bw);
        }
        asm volatile("s_waitcnt lgkmcnt(0)" ::: "memory");
        __builtin_amdgcn_sched_barrier(0);

        #pragma unroll
        for (int mi = 0; mi < 4; ++mi) {
            #pragma unroll
            for (int ni = 0; ni < 4; ++ni)
                acc[mi][ni] = __builtin_amdgcn_mfma_f32_16x16x32_bf16(af[mi], bfv[ni], acc[mi][ni], 0, 0, 0);
        }
    }

    int pr = p >> 3, pc = p & 7;
    #pragma unroll
    for (int mi = 0; mi < 4; ++mi) {
        #pragma unroll
        for (int r = 0; r < 4; ++r) {
            int n = n0 + wr * 64 + mi * 16 + ((lane >> 4) << 2) + r;
            if (n >= NW) continue;
            float* obase;
            if (n < N1) {
                obase = out + (((size_t)b * 128 + (n >> 4) * 8 + pr) * 128 + ((n & 15) << 3) + pc) * 256;
            } else {
                int nn = n - N1;
                obase = out + OUT2_OFF + (((size_t)b * 96 + (nn / 12) * 8 + pr) * 96 + (nn % 12) * 8 + pc) * 256;
            }
            #pragma unroll
            for (int ni = 0; ni < 4; ++ni)
                obase[d0 + wc * 64 + ni * 16 + l15] = acc[mi][ni][r];
        }
    }
}

// ---------------------------------------------------------------------------
extern "C" void kernel_launch(void* const* d_in, const int* in_sizes, int n_in,
                              void* d_out, int out_size, void* d_ws, size_t ws_size,
                              hipStream_t stream) {
    const float* x1    = (const float*)d_in[0];
    const float* c1    = (const float*)d_in[1];
    const float* x2    = (const float*)d_in[2];
    const float* c2    = (const float*)d_in[3];
    const float* fqk_w = (const float*)d_in[4];
    const float* fqk_b = (const float*)d_in[5];
    const float* fqk_g = (const float*)d_in[6];
    const float* cqk_w = (const float*)d_in[7];
    const float* cqk_b = (const float*)d_in[8];
    const float* cqk_g = (const float*)d_in[9];
    const float* v_w   = (const float*)d_in[10];
    const float* vb_w  = (const float*)d_in[11];
    float* out = (float*)d_out;

    char* wsb = (char*)d_ws;
    short* Mbf    = (short*)(wsb);                    //     131,072 B
    short* fqk_wb = (short*)(wsb + 131072);           //     262,144 B
    short* favgb  = (short*)(wsb + 393216);           //     819,200 B
    short* qcat   = (short*)(wsb + 1212416);          //   1,638,400 B
    short* kcat   = (short*)(wsb + 2850816);          //   1,638,400 B
    short* Pb     = (short*)(wsb + 4489216);          //  13,631,488 B
    short* Wb     = (short*)(wsb + 18120704);         //  52,428,800 B (ends 70,549,504)

    prep_kernel<<<256, 256, 0, stream>>>(v_w, vb_w, Mbf);
    wconv_kernel<<<512, 256, 0, stream>>>(fqk_w, fqk_wb);
    mean_kernel<<<B * NW, 256, 0, stream>>>(x1, c1, x2, c2, cqk_w, cqk_b, cqk_g,
                                            favgb, qcat, kcat);
    qkproj_kernel<<<50, 256, 0, stream>>>(fqk_wb, fqk_b, fqk_g, favgb, qcat, kcat);
    wproj_mfma<<<1600, 256, 0, stream>>>(x1, x2, Mbf, Wb);
    scores_kernel<<<200, 256, 0, stream>>>(qcat, kcat, Pb);
    pv_mfma<<<2048, 256, 0, stream>>>(Pb, Wb, out);
}

// Round 9
// 311.601 us; speedup vs baseline: 2.1220x; 1.1012x over previous
//
#include <hip/hip_runtime.h>
#include <hip/hip_bf16.h>

#define B 4
#define NH 8
#define N1 256
#define N2 144
#define NW 400
#define OUT2_OFF ((size_t)16777216)   // 4*128*128*256

typedef __attribute__((ext_vector_type(8))) short short8v;
typedef __attribute__((ext_vector_type(4))) float f32x4;
typedef __attribute__((ext_vector_type(2))) unsigned uint2v;
typedef __attribute__((ext_vector_type(4))) unsigned uint4v;

static __device__ __forceinline__ short f2bf(float f) {
    __hip_bfloat16 h = __float2bfloat16(f);
    return __builtin_bit_cast(short, h);
}

// row base for (window n, pixel p), channel 0
static __device__ __forceinline__ const float* xrow_ptr(const float* x1, const float* x2,
                                                        int b, int n, int p) {
    if (n < N1)
        return x1 + (((size_t)b * 128 + (n >> 4) * 8 + (p >> 3)) * 128 + (n & 15) * 8 + (p & 7)) * 256;
    int nn = n - N1;
    return x2 + (((size_t)b * 96 + (nn / 12) * 8 + (p >> 3)) * 96 + (nn % 12) * 8 + (p & 7)) * 256;
}

// ---------------------------------------------------------------------------
// setup_kernel: fused prep (Mbf, bid<256) + wconv (fqk_wb, bid 256..767)
//             + mean (favgb/coordQK, bid 768..2367). Block-uniform branches.
// ---------------------------------------------------------------------------
__global__ void setup_kernel(const float* __restrict__ v_w, const float* __restrict__ vb_w,
                             const float* __restrict__ fqk_w,
                             const float* __restrict__ x1, const float* __restrict__ c1,
                             const float* __restrict__ x2, const float* __restrict__ c2,
                             const float* __restrict__ cqk_w, const float* __restrict__ cqk_b,
                             const float* __restrict__ cqk_g,
                             short* __restrict__ Mbf, short* __restrict__ fqk_wb,
                             short* __restrict__ favgb,
                             short* __restrict__ qcat, short* __restrict__ kcat) {
    int bid = blockIdx.x;
    int t = threadIdx.x;

    __shared__ float cavg[4];
    __shared__ float red[256];

    if (bid < 256) {
        // prep: M = vb_w @ v_w, MFMA-A-frag order
        int d = bid, k = t;
        float s = 0.f;
        for (int j = 0; j < 256; ++j)
            s += vb_w[d * 256 + j] * v_w[j * 256 + k];
        size_t idx = ((((size_t)((d >> 4) * 8 + (k >> 5))) * 4 + ((k >> 3) & 3)) * 16 + (d & 15)) * 8 + (k & 7);
        Mbf[idx] = f2bf(s);
        return;
    }
    if (bid < 768) {
        int i = (bid - 256) * 256 + t;
        fqk_wb[i] = f2bf(fqk_w[i]);
        return;
    }

    int blk = bid - 768;
    int b = blk / NW, n = blk % NW;

    const float* xbase;
    int rstride;
    if (n < N1) {
        xbase = x1 + (((size_t)b * 128 + (n >> 4) * 8) * 128 + (n & 15) * 8) * 256;
        rstride = 128 * 256;
    } else {
        int nn = n - N1;
        xbase = x2 + (((size_t)b * 96 + (nn / 12) * 8) * 96 + (nn % 12) * 8) * 256;
        rstride = 96 * 256;
    }

    float a0 = 0.f, a1 = 0.f, a2 = 0.f, a3 = 0.f;
    #pragma unroll
    for (int pr = 0; pr < 8; ++pr) {
        const float* rowp = xbase + (size_t)pr * rstride + t;
        a0 += rowp[0 * 256] + rowp[4 * 256];
        a1 += rowp[1 * 256] + rowp[5 * 256];
        a2 += rowp[2 * 256] + rowp[6 * 256];
        a3 += rowp[3 * 256] + rowp[7 * 256];
    }
    favgb[(size_t)blk * 256 + t] = f2bf((a0 + a1 + a2 + a3) * (1.f / 64.f));

    if (t < 64) {
        const float* cbase;
        int crs;
        if (n < N1) {
            cbase = c1 + (((size_t)b * 128 + (n >> 4) * 8) * 128 + (n & 15) * 8) * 4;
            crs = 128 * 4;
        } else {
            int nn = n - N1;
            cbase = c2 + (((size_t)b * 96 + (nn / 12) * 8) * 96 + (nn % 12) * 8) * 4;
            crs = 96 * 4;
        }
        float4 v = *(const float4*)(cbase + (t >> 3) * crs + (t & 7) * 4);
        for (int off = 32; off > 0; off >>= 1) {
            v.x += __shfl_down(v.x, off, 64);
            v.y += __shfl_down(v.y, off, 64);
            v.z += __shfl_down(v.z, off, 64);
            v.w += __shfl_down(v.w, off, 64);
        }
        if (t == 0) {
            cavg[0] = v.x * (1.f / 64.f);
            cavg[1] = v.y * (1.f / 64.f);
            cavg[2] = v.z * (1.f / 64.f);
            cavg[3] = v.w * (1.f / 64.f);
        }
    }
    __syncthreads();

    float co = 0.f;
    if (t < 128) {
        co = cqk_b[t];
        #pragma unroll
        for (int k = 0; k < 4; ++k) co += cavg[k] * cqk_w[t * 4 + k];
    }
    red[t] = (t < 128) ? co * co : 0.f;
    __syncthreads();
    for (int s = 128; s > 0; s >>= 1) {
        if (t < s) red[t] += red[t + s];
        __syncthreads();
    }
    float cscale = rsqrtf(red[0] / 128.f + 1e-6f);

    const float SC = 0.35355339059327373f;   // 1/sqrt(8)
    if (t < 64) {
        int h = t >> 3, j = 32 + (t & 7);
        qcat[((size_t)(b * 8 + h) * NW + n) * 64 + j] = f2bf(co * cscale * cqk_g[t] * SC);
    } else if (t < 128) {
        int tt = t - 64;
        int h = tt >> 3, j = 32 + (tt & 7);
        kcat[((size_t)(b * 8 + h) * NW + n) * 64 + j] = f2bf(co * cscale * cqk_g[t]);
    } else {
        int tt = t - 128;
        for (int z = tt; z < 384; z += 128) {
            int which = z & 1;
            int zz = z >> 1;
            int h = zz / 24, j = 40 + zz % 24;
            short* dst = which ? kcat : qcat;
            dst[((size_t)(b * 8 + h) * NW + n) * 64 + j] = 0;
        }
    }
}

// ---------------------------------------------------------------------------
// projw_kernel: fused qkproj (bid<50) + wproj (bid 50..1649). 256 threads.
// ---------------------------------------------------------------------------
__global__ __launch_bounds__(256, 2) void projw_kernel(
    const short* __restrict__ fqk_wb, const float* __restrict__ fqk_b,
    const float* __restrict__ fqk_g, const short* __restrict__ favgb,
    short* __restrict__ qcat, short* __restrict__ kcat,
    const float* __restrict__ x1, const float* __restrict__ x2,
    const short* __restrict__ Mbf, short* __restrict__ Wb) {
    __shared__ short lds[2][128][40];     // wproj staging (20KB)
    __shared__ float ssb[2][2][16];       // qkproj reduce

    int tid = threadIdx.x;
    int lane = tid & 63, w = tid >> 6;
    int l15 = lane & 15, g = lane >> 4;

    if (blockIdx.x < 50) {
        // ---------------- qkproj ----------------
        int ngl = w >> 1, half = w & 1;
        int ngrp = blockIdx.x * 2 + ngl;

        const short* frow = favgb + ((size_t)ngrp * 16 + l15) * 256;
        short8v bf[8];
        #pragma unroll
        for (int c = 0; c < 8; ++c) bf[c] = *(const short8v*)(frow + c * 32 + g * 8);

        f32x4 acc[16];
        #pragma unroll
        for (int i = 0; i < 16; ++i) acc[i] = (f32x4)0.f;

        #pragma unroll
        for (int mt = 0; mt < 16; ++mt) {
            const short* arow = fqk_wb + ((size_t)(half * 256 + mt * 16 + l15)) * 256;
            #pragma unroll
            for (int c = 0; c < 8; ++c) {
                short8v af = *(const short8v*)(arow + c * 32 + g * 8);
                acc[mt] = __builtin_amdgcn_mfma_f32_16x16x32_bf16(af, bf[c], acc[mt], 0, 0, 0);
            }
        }

        float ss = 0.f;
        #pragma unroll
        for (int mt = 0; mt < 16; ++mt) {
            float4 bi = *(const float4*)(fqk_b + half * 256 + mt * 16 + g * 4);
            acc[mt][0] += bi.x; acc[mt][1] += bi.y; acc[mt][2] += bi.z; acc[mt][3] += bi.w;
            ss += acc[mt][0] * acc[mt][0] + acc[mt][1] * acc[mt][1]
                + acc[mt][2] * acc[mt][2] + acc[mt][3] * acc[mt][3];
        }
        ss += __shfl_xor(ss, 16, 64);
        ss += __shfl_xor(ss, 32, 64);
        if (lane < 16) ssb[ngl][half][lane] = ss;
        __syncthreads();
        float scale = rsqrtf((ssb[ngl][0][l15] + ssb[ngl][1][l15]) / 512.f + 1e-6f);

        int idx = ngrp * 16 + l15;
        int b = idx / NW, n = idx % NW;
        const float SF = 0.17677669529663687f;   // 1/sqrt(32), folded into q
        float mult = half ? 1.f : SF;
        short* dst = half ? kcat : qcat;

        #pragma unroll
        for (int mt = 0; mt < 16; ++mt) {
            int ol = mt * 16 + g * 4;
            float4 gg = *(const float4*)(fqk_g + half * 256 + ol);
            int h = ol >> 5, j = ol & 31;
            short4 s4 = make_short4(f2bf(acc[mt][0] * scale * gg.x * mult),
                                    f2bf(acc[mt][1] * scale * gg.y * mult),
                                    f2bf(acc[mt][2] * scale * gg.z * mult),
                                    f2bf(acc[mt][3] * scale * gg.w * mult));
            *(short4*)(dst + ((size_t)(b * 8 + h) * NW + n) * 64 + j) = s4;
        }
        return;
    }

    // ---------------- wproj ----------------
    int bid = blockIdx.x - 50;
    int dt = bid & 1, rh = (bid >> 1) & 1, rt = bid >> 2;
    int wd = w & 1, wrR = w >> 1;

    int b = rt / 100;
    int nb0 = (rt % 100) * 4 + rh * 2;

    int Rl0 = tid >> 2, oc = tid & 3;
    int Rl1 = Rl0 + 64;
    const float* src0 = xrow_ptr(x1, x2, b, nb0 + (Rl0 >> 6), Rl0 & 63) + oc * 8;
    const float* src1 = xrow_ptr(x1, x2, b, nb0 + (Rl1 >> 6), Rl1 & 63) + oc * 8;

    float4 p00 = *(const float4*)(src0);
    float4 p01 = *(const float4*)(src0 + 4);
    float4 p10 = *(const float4*)(src1);
    float4 p11 = *(const float4*)(src1 + 4);

    f32x4 acc[4][4] = {};
    for (int kc = 0; kc < 8; ++kc) {
        int buf = kc & 1;
        short8v s0, s1;
        s0[0] = f2bf(p00.x); s0[1] = f2bf(p00.y); s0[2] = f2bf(p00.z); s0[3] = f2bf(p00.w);
        s0[4] = f2bf(p01.x); s0[5] = f2bf(p01.y); s0[6] = f2bf(p01.z); s0[7] = f2bf(p01.w);
        s1[0] = f2bf(p10.x); s1[1] = f2bf(p10.y); s1[2] = f2bf(p10.z); s1[3] = f2bf(p10.w);
        s1[4] = f2bf(p11.x); s1[5] = f2bf(p11.y); s1[6] = f2bf(p11.z); s1[7] = f2bf(p11.w);
        *(short8v*)&lds[buf][Rl0][oc * 8] = s0;
        *(short8v*)&lds[buf][Rl1][oc * 8] = s1;
        if (kc < 7) {
            const float* q0 = src0 + (kc + 1) * 32;
            const float* q1 = src1 + (kc + 1) * 32;
            p00 = *(const float4*)q0; p01 = *(const float4*)(q0 + 4);
            p10 = *(const float4*)q1; p11 = *(const float4*)(q1 + 4);
        }
        short8v af[4];
        #pragma unroll
        for (int mi = 0; mi < 4; ++mi) {
            int dtile = dt * 8 + wd * 4 + mi;
            af[mi] = *(const short8v*)(Mbf + ((size_t)(dtile * 8 + kc)) * 512 + lane * 8);
        }
        __syncthreads();
        #pragma unroll
        for (int ni = 0; ni < 4; ++ni) {
            int Rl = wrR * 64 + ni * 16 + l15;
            short8v bfv = *(const short8v*)&lds[buf][Rl][g * 8];
            #pragma unroll
            for (int mi = 0; mi < 4; ++mi)
                acc[mi][ni] = __builtin_amdgcn_mfma_f32_16x16x32_bf16(af[mi], bfv, acc[mi][ni], 0, 0, 0);
        }
    }

    int dq = dt * 128 + wd * 64 + g * 4;
    #pragma unroll
    for (int ni = 0; ni < 4; ++ni) {
        size_t Rg = (size_t)rt * 256 + rh * 128 + wrR * 64 + ni * 16 + l15;
        short* wp = Wb + Rg * 256 + dq;
        #pragma unroll
        for (int mi = 0; mi < 4; ++mi) {
            f32x4 a = acc[mi][ni];
            *(short4*)(wp + mi * 16) = make_short4(f2bf(a[0]), f2bf(a[1]), f2bf(a[2]), f2bf(a[3]));
        }
    }
}

// ---------------------------------------------------------------------------
// scores: swapped-operand MFMA, softmax over m in-register. (unchanged)
// ---------------------------------------------------------------------------
template <int NMT>
static __device__ __forceinline__ void scores_wave(const short* __restrict__ qcat,
                                                   const short* __restrict__ kcat,
                                                   short* __restrict__ Pb,
                                                   int b, int h, int n0, int mbase, int lane) {
    int l15 = lane & 15, g = lane >> 4;
    int kl8 = g * 8;
    size_t rowb = (size_t)(b * 8 + h) * NW;

    const short* qrow = qcat + (rowb + n0 + l15) * 64;
    short8v bf0 = *(const short8v*)(qrow + kl8);
    short8v bf1 = *(const short8v*)(qrow + 32 + kl8);

    f32x4 acc[NMT];
    #pragma unroll
    for (int i = 0; i < NMT; ++i) acc[i] = (f32x4)0.f;

    #pragma unroll
    for (int mt = 0; mt < NMT; ++mt) {
        const short* krow = kcat + (rowb + mbase + mt * 16 + l15) * 64;
        short8v af0 = *(const short8v*)(krow + kl8);
        short8v af1 = *(const short8v*)(krow + 32 + kl8);
        acc[mt] = __builtin_amdgcn_mfma_f32_16x16x32_bf16(af0, bf0, acc[mt], 0, 0, 0);
        acc[mt] = __builtin_amdgcn_mfma_f32_16x16x32_bf16(af1, bf1, acc[mt], 0, 0, 0);
    }

    float mx = -3.4e38f;
    #pragma unroll
    for (int mt = 0; mt < NMT; ++mt)
        #pragma unroll
        for (int r = 0; r < 4; ++r) mx = fmaxf(mx, acc[mt][r]);
    mx = fmaxf(mx, __shfl_xor(mx, 16, 64));
    mx = fmaxf(mx, __shfl_xor(mx, 32, 64));

    float sum = 0.f;
    #pragma unroll
    for (int mt = 0; mt < NMT; ++mt)
        #pragma unroll
        for (int r = 0; r < 4; ++r) {
            float e = __expf(acc[mt][r] - mx);
            acc[mt][r] = e;
            sum += e;
        }
    sum += __shfl_xor(sum, 16, 64);
    sum += __shfl_xor(sum, 32, 64);
    float inv = 1.f / sum;

    int n = n0 + l15;
    short* prow = Pb + ((size_t)(b * 8 + h) * 512 + n) * 416;
    #pragma unroll
    for (int mt = 0; mt < NMT; ++mt) {
        int m = mbase + mt * 16 + g * 4;
        *(short4*)(prow + m) = make_short4(f2bf(acc[mt][0] * inv), f2bf(acc[mt][1] * inv),
                                           f2bf(acc[mt][2] * inv), f2bf(acc[mt][3] * inv));
    }
}

__global__ __launch_bounds__(256) void scores_kernel(const short* __restrict__ qcat,
                                                     const short* __restrict__ kcat,
                                                     short* __restrict__ Pb) {
    int wid = blockIdx.x * 4 + (threadIdx.x >> 6);
    int lane = threadIdx.x & 63;
    if (wid < 512) {
        int b = wid >> 7, h = (wid >> 4) & 7, n0 = (wid & 15) * 16;
        scores_wave<9>(qcat, kcat, Pb, b, h, n0, 256, lane);
    } else {
        int t3 = wid - 512;
        int b = t3 / 72, r = t3 % 72;
        int h = r / 9, n0 = 256 + (r % 9) * 16;
        scores_wave<16>(qcat, kcat, Pb, b, h, n0, 0, lane);
    }
}

// ---------------------------------------------------------------------------
// pv v2: 512-thread blocks, 256 n-rows share one staged W m-tile.
// grid = b4 x p64 x half2 x dt2 = 1024. Waves: wr=w>>1 (n-group), wc=w&1 (d-half).
// half0: n in [0,256), m in [256,400); half1: n in [256,512) (write-guarded), m in [0,256).
// ---------------------------------------------------------------------------
__global__ __launch_bounds__(512) void pv_mfma(
    const short* __restrict__ Pb, const short* __restrict__ Wb,
    float* __restrict__ out) {
    int bid = blockIdx.x;
    int dt   = bid & 1;
    int half = (bid >> 1) & 1;
    int p    = (bid >> 2) & 63;
    int b    = bid >> 8;
    int h    = p >> 3;
    int tid = threadIdx.x;
    int lane = tid & 63;
    int w = tid >> 6;                 // 0..7
    int wr = w >> 1;                  // n-group 0..3
    int wc = w & 1;                   // d-half 0..1
    int l15 = lane & 15;
    int kl8 = (lane >> 4) << 3;

    __shared__ short8v Bs[512];       // 8KB [par2][nb8][32chunks]
    unsigned ldsBase = (unsigned)(size_t)&Bs[0];

    int n0 = half * 256;
    int mlo = half ? 0 : 256;
    int mhi = half ? 256 : 400;
    int d0 = dt * 128;

    const short* arow[4];
    #pragma unroll
    for (int mi = 0; mi < 4; ++mi) {
        int n = n0 + wr * 64 + mi * 16 + l15;
        arow[mi] = Pb + ((size_t)(b * 8 + h) * 512 + n) * 416 + kl8;
    }

    f32x4 acc[4][4] = {};

    // one 16B chunk per thread: mrow = tid>>4 (0..31), doff = (tid&15)*8 shorts
    int mrow0 = tid >> 4;
    int doff0 = (tid & 15) << 3;
    int par = (mrow0 >> 2) & 1, gg = mrow0 >> 3, r = mrow0 & 3;
    int nb = doff0 >> 4, c0h = (doff0 >> 3) & 1;
    int bsIdx = (par * 8 + nb) * 32 + gg * 8 + r * 2 + c0h;

    const size_t wbBase = ((size_t)b * 400) * 64 * 256 + (size_t)p * 256 + d0;

    short8v cur0;
    {
        int gm0 = mlo + mrow0;
        cur0 = (gm0 < mhi) ? *(const short8v*)(Wb + wbBase + (size_t)gm0 * 64 * 256 + doff0) : (short8v)0;
    }

    for (int m0 = mlo; m0 < mhi; m0 += 32) {
        short8v af[4];
        #pragma unroll
        for (int mi = 0; mi < 4; ++mi)
            af[mi] = *(const short8v*)(arow[mi] + m0);

        __syncthreads();                  // prev iteration's readers done
        Bs[bsIdx] = cur0;
        if (m0 + 32 < mhi) {
            int gm0 = m0 + 32 + mrow0;
            cur0 = (gm0 < mhi) ? *(const short8v*)(Wb + wbBase + (size_t)gm0 * 64 * 256 + doff0) : (short8v)0;
        }
        __syncthreads();                  // tile ready

        short8v bfv[4];
        #pragma unroll
        for (int ni = 0; ni < 4; ++ni) {
            int nbr = wc * 4 + ni;
            unsigned a0 = ldsBase + (unsigned)((0 * 8 + nbr) * 512 + lane * 8);
            unsigned a1 = ldsBase + (unsigned)((1 * 8 + nbr) * 512 + lane * 8);
            uint2v lo, hi;
            asm volatile("ds_read_b64_tr_b16 %0, %1" : "=v"(lo) : "v"(a0));
            asm volatile("ds_read_b64_tr_b16 %0, %1" : "=v"(hi) : "v"(a1));
            uint4v bw; bw.x = lo.x; bw.y = lo.y; bw.z = hi.x; bw.w = hi.y;
            bfv[ni] = __builtin_bit_cast(short8v, bw);
        }
        asm volatile("s_waitcnt lgkmcnt(0)" ::: "memory");
        __builtin_amdgcn_sched_barrier(0);

        #pragma unroll
        for (int mi = 0; mi < 4; ++mi) {
            #pragma unroll
            for (int ni = 0; ni < 4; ++ni)
                acc[mi][ni] = __builtin_amdgcn_mfma_f32_16x16x32_bf16(af[mi], bfv[ni], acc[mi][ni], 0, 0, 0);
        }
    }

    int pr = p >> 3, pc = p & 7;
    #pragma unroll
    for (int mi = 0; mi < 4; ++mi) {
        #pragma unroll
        for (int rr = 0; rr < 4; ++rr) {
            int n = n0 + wr * 64 + mi * 16 + ((lane >> 4) << 2) + rr;
            if (n >= NW) continue;
            float* obase;
            if (n < N1) {
                obase = out + (((size_t)b * 128 + (n >> 4) * 8 + pr) * 128 + ((n & 15) << 3) + pc) * 256;
            } else {
                int nn = n - N1;
                obase = out + OUT2_OFF + (((size_t)b * 96 + (nn / 12) * 8 + pr) * 96 + (nn % 12) * 8 + pc) * 256;
            }
            #pragma unroll
            for (int ni = 0; ni < 4; ++ni)
                obase[d0 + wc * 64 + ni * 16 + l15] = acc[mi][ni][rr];
        }
    }
}

// ---------------------------------------------------------------------------
extern "C" void kernel_launch(void* const* d_in, const int* in_sizes, int n_in,
                              void* d_out, int out_size, void* d_ws, size_t ws_size,
                              hipStream_t stream) {
    const float* x1    = (const float*)d_in[0];
    const float* c1    = (const float*)d_in[1];
    const float* x2    = (const float*)d_in[2];
    const float* c2    = (const float*)d_in[3];
    const float* fqk_w = (const float*)d_in[4];
    const float* fqk_b = (const float*)d_in[5];
    const float* fqk_g = (const float*)d_in[6];
    const float* cqk_w = (const float*)d_in[7];
    const float* cqk_b = (const float*)d_in[8];
    const float* cqk_g = (const float*)d_in[9];
    const float* v_w   = (const float*)d_in[10];
    const float* vb_w  = (const float*)d_in[11];
    float* out = (float*)d_out;

    char* wsb = (char*)d_ws;
    short* Mbf    = (short*)(wsb);                    //     131,072 B
    short* fqk_wb = (short*)(wsb + 131072);           //     262,144 B
    short* favgb  = (short*)(wsb + 393216);           //     819,200 B
    short* qcat   = (short*)(wsb + 1212416);          //   1,638,400 B
    short* kcat   = (short*)(wsb + 2850816);          //   1,638,400 B
    short* Pb     = (short*)(wsb + 4489216);          //  13,631,488 B
    short* Wb     = (short*)(wsb + 18120704);         //  52,428,800 B (ends 70,549,504)

    setup_kernel<<<2368, 256, 0, stream>>>(v_w, vb_w, fqk_w, x1, c1, x2, c2,
                                           cqk_w, cqk_b, cqk_g,
                                           Mbf, fqk_wb, favgb, qcat, kcat);
    projw_kernel<<<1650, 256, 0, stream>>>(fqk_wb, fqk_b, fqk_g, favgb, qcat, kcat,
                                           x1, x2, Mbf, Wb);
    scores_kernel<<<200, 256, 0, stream>>>(qcat, kcat, Pb);
    pv_mfma<<<1024, 512, 0, stream>>>(Pb, Wb, out);
}